// Round 11
// baseline (227.363 us; speedup 1.0000x reference)
//
#include <hip/hip_runtime.h>

// ---------------------------------------------------------------------------
// HeteroGNN, round 11: deeper gather ILP + tail-balanced final GEMM.
//   out = relu( [mean_i | mean_t | x_user] @ [Wl_i; Wl_t; W_user@(Wr_i+Wr_t)]
//               + (b_user@(Wr_i+Wr_t) + bl_i + bl_t) )        [MFMA, K=512]
// CSR: two-level bucket partition, zero global atomics (r9).
// gather: 8 lanes/node, 32B/lane, unroll-4 (8 loads in flight/thread).
// final: 256 thr / 128 rows / 32KB B-quarters staged in LDS; grid 782.
// k_pack fused into k_front as a block range.
// MFMA 16x16x32_bf16: A row=lane&15, k=(lane>>4)*8+j; B col=lane&15;
// D col=lane&15, row=(lane>>4)*4+reg  [m89-verified].
// ---------------------------------------------------------------------------

#define BK 4096          // edges per level-1 block
#define MAXBUK 256       // >= nbuk = ceil(2N/1024) = 196

typedef __attribute__((ext_vector_type(8))) short bf16x8;
typedef __attribute__((ext_vector_type(8))) unsigned short u16x8;
typedef __attribute__((ext_vector_type(4))) float f32x4;

__device__ __forceinline__ ushort f2b(float x) {
    union { float f; unsigned u; } v; v.f = x;
    unsigned r = (v.u + 0x7FFF + ((v.u >> 16) & 1)) >> 16;   // RNE
    return (ushort)r;
}
__device__ __forceinline__ float b2f(ushort u) {
    union { unsigned u; float f; } v; v.u = (unsigned)u << 16;
    return v.f;
}

// ---- fused front: [bucket hist (LDS) | bf16 convert | weight pack] ----
__global__ __launch_bounds__(256) void k_front(
        const float* __restrict__ x_image, const float* __restrict__ x_text,
        const int* __restrict__ edge_i, const int* __restrict__ edge_t,
        const float* __restrict__ Wl_i, const float* __restrict__ Wl_t,
        const float* __restrict__ W_user, const float* __restrict__ b_user,
        const float* __restrict__ Wr_i, const float* __restrict__ Wr_t,
        const float* __restrict__ bl_i, const float* __restrict__ bl_t,
        ushort* __restrict__ xib, ushort* __restrict__ xtb,
        ushort* __restrict__ Bp, float* __restrict__ bias,
        int* __restrict__ counts,
        int N, int E, int nblkR, int nbuk, int nbC) {
    __shared__ int h[MAXBUK];
    const int bid = blockIdx.x;
    const int tid = threadIdx.x;
    const int NBLK = 2 * nblkR;

    if (bid < NBLK) {
        // ---- level-1 histogram of bucket = key>>10, LDS atomics only ----
        int rel = (bid >= nblkR) ? 1 : 0;
        int blk = bid - rel * nblkR;
        const int* eg = rel ? edge_t : edge_i;
        const int relN = rel * N;
        for (int i = tid; i < nbuk; i += 256) h[i] = 0;
        __syncthreads();
        int base = blk * BK;
        #pragma unroll
        for (int j = 0; j < 4; ++j) {
            int e = base + (j * 256 + tid) * 4;
            if (e + 3 < E) {
                int4 d4 = *reinterpret_cast<const int4*>(eg + E + e);
                atomicAdd(&h[(relN + d4.x) >> 10], 1);
                atomicAdd(&h[(relN + d4.y) >> 10], 1);
                atomicAdd(&h[(relN + d4.z) >> 10], 1);
                atomicAdd(&h[(relN + d4.w) >> 10], 1);
            } else {
                for (int q = 0; q < 4; ++q) {
                    int ee = e + q;
                    if (ee < E) atomicAdd(&h[(relN + eg[E + ee]) >> 10], 1);
                }
            }
        }
        __syncthreads();
        for (int i = tid; i < nbuk; i += 256) counts[(size_t)bid * nbuk + i] = h[i];
    } else if (bid < NBLK + nbC) {
        // ---- x_image/x_text f32 -> bf16 ----
        int t = (bid - NBLK) * 256 + tid;
        int n8 = N * 16;
        if (t >= 2 * n8) return;
        int relc = (t >= n8) ? 1 : 0;
        const float* src = relc ? x_text : x_image;
        ushort* dst = relc ? xtb : xib;
        int i = relc ? t - n8 : t;
        float4 f0 = *reinterpret_cast<const float4*>(src + (size_t)i * 8);
        float4 f1 = *reinterpret_cast<const float4*>(src + (size_t)i * 8 + 4);
        u16x8 o;
        o[0] = f2b(f0.x); o[1] = f2b(f0.y); o[2] = f2b(f0.z); o[3] = f2b(f0.w);
        o[4] = f2b(f1.x); o[5] = f2b(f1.y); o[6] = f2b(f1.z); o[7] = f2b(f1.w);
        *reinterpret_cast<u16x8*>(dst + (size_t)i * 8) = o;
    } else {
        // ---- pack Bp [512x128] = [Wl_i; Wl_t; W_user@(Wr_i+Wr_t)] + bias ----
        int i = (bid - NBLK - nbC) * 256 + tid;      // < 65536
        int j = i & 7, lane = (i >> 3) & 63, cf = (i >> 9) & 7, ks = i >> 12;
        int kk = ks * 32 + (lane >> 4) * 8 + j;
        int col = cf * 16 + (lane & 15);
        float v;
        if (kk < 128)      v = Wl_i[kk * 128 + col];
        else if (kk < 256) v = Wl_t[(kk - 128) * 128 + col];
        else {
            int k2 = kk - 256;
            float s = 0.f;
            for (int c1 = 0; c1 < 128; ++c1)
                s += W_user[k2 * 128 + c1] * (Wr_i[c1 * 128 + col] + Wr_t[c1 * 128 + col]);
            v = s;
        }
        Bp[i] = f2b(v);
        if (i < 128) {
            float b = bl_i[i] + bl_t[i];
            for (int k2 = 0; k2 < 128; ++k2)
                b += b_user[k2] * (Wr_i[k2 * 128 + i] + Wr_t[k2 * 128 + i]);
            bias[i] = b;
        }
    }
}

// ---- s1: per-bucket exclusive prefix over blocks (in-place) + totals ----
__global__ __launch_bounds__(256) void k_s1(int* __restrict__ counts,
                                            int* __restrict__ T,
                                            int NBLK, int nbuk) {
    __shared__ int a[512];
    __shared__ int ps[256];
    const int b = blockIdx.x, t = threadIdx.x;
    a[t]       = (t < NBLK)       ? counts[(size_t)t * nbuk + b] : 0;
    a[t + 256] = (t + 256 < NBLK) ? counts[(size_t)(t + 256) * nbuk + b] : 0;
    __syncthreads();
    int x0 = a[2 * t], x1 = a[2 * t + 1];
    int s = x0 + x1;
    ps[t] = s; __syncthreads();
    for (int off = 1; off < 256; off <<= 1) {
        int add = (t >= off) ? ps[t - off] : 0;
        __syncthreads();
        ps[t] += add;
        __syncthreads();
    }
    int ex = ps[t] - s;
    if (2 * t < NBLK)     counts[(size_t)(2 * t) * nbuk + b] = ex;
    if (2 * t + 1 < NBLK) counts[(size_t)(2 * t + 1) * nbuk + b] = ex + x0;
    if (t == 255) T[b] = ps[255];
}

// ---- s2: exclusive scan of bucket totals -> bucket bases ----
__global__ __launch_bounds__(256) void k_s2(const int* __restrict__ T,
                                            int* __restrict__ Bb,
                                            int* __restrict__ rowptr,
                                            int M, int Etot, int nbuk) {
    __shared__ int sh[256];
    int t = threadIdx.x;
    int v = (t < nbuk) ? T[t] : 0;
    sh[t] = v; __syncthreads();
    for (int off = 1; off < 256; off <<= 1) {
        int add = (t >= off) ? sh[t - off] : 0;
        __syncthreads();
        sh[t] += add;
        __syncthreads();
    }
    if (t < nbuk) Bb[t] = sh[t] - v;
    if (t == 0) { Bb[nbuk] = Etot; rowptr[M] = Etot; }
}

// ---- part1: scatter (key,src) pairs into bucket regions via LDS cursors ----
__global__ __launch_bounds__(256) void k_part1(
        const int* __restrict__ edge_i, const int* __restrict__ edge_t,
        const int* __restrict__ counts, const int* __restrict__ Bb,
        int2* __restrict__ pairs, int N, int E, int nblkR, int nbuk) {
    __shared__ int cur[MAXBUK];
    const int bid = blockIdx.x, tid = threadIdx.x;
    int rel = (bid >= nblkR) ? 1 : 0;
    int blk = bid - rel * nblkR;
    const int* eg = rel ? edge_t : edge_i;
    const int relN = rel * N;
    for (int i = tid; i < nbuk; i += 256)
        cur[i] = Bb[i] + counts[(size_t)bid * nbuk + i];
    __syncthreads();
    int base = blk * BK;
    #pragma unroll
    for (int j = 0; j < 4; ++j) {
        int e = base + (j * 256 + tid) * 4;
        if (e + 3 < E) {
            int4 d4 = *reinterpret_cast<const int4*>(eg + E + e);
            int4 s4 = *reinterpret_cast<const int4*>(eg + e);
            int k0 = relN + d4.x, k1 = relN + d4.y, k2 = relN + d4.z, k3 = relN + d4.w;
            int p0 = atomicAdd(&cur[k0 >> 10], 1); pairs[p0] = make_int2(k0, s4.x);
            int p1 = atomicAdd(&cur[k1 >> 10], 1); pairs[p1] = make_int2(k1, s4.y);
            int p2 = atomicAdd(&cur[k2 >> 10], 1); pairs[p2] = make_int2(k2, s4.z);
            int p3 = atomicAdd(&cur[k3 >> 10], 1); pairs[p3] = make_int2(k3, s4.w);
        } else {
            for (int q = 0; q < 4; ++q) {
                int ee = e + q;
                if (ee < E) {
                    int k0 = relN + eg[E + ee];
                    int p0 = atomicAdd(&cur[k0 >> 10], 1);
                    pairs[p0] = make_int2(k0, eg[ee]);
                }
            }
        }
    }
}

// ---- part2: per-bucket (1024 keys) hist/scan -> rowptr + col ----
__global__ __launch_bounds__(256) void k_part2(
        const int2* __restrict__ pairs, const int* __restrict__ Bb,
        int* __restrict__ rowptr, int* __restrict__ col, int M) {
    __shared__ int h[1024];
    __shared__ int ps[256];
    const int b = blockIdx.x, t = threadIdx.x;
    const int key0 = b << 10;
    const int beg = Bb[b], end = Bb[b + 1];
    for (int i = t; i < 1024; i += 256) h[i] = 0;
    __syncthreads();
    for (int p = beg + t; p < end; p += 256)
        atomicAdd(&h[pairs[p].x - key0], 1);
    __syncthreads();
    int v0 = h[4 * t], v1 = h[4 * t + 1], v2 = h[4 * t + 2], v3 = h[4 * t + 3];
    int s = v0 + v1 + v2 + v3;
    ps[t] = s; __syncthreads();
    for (int off = 1; off < 256; off <<= 1) {
        int add = (t >= off) ? ps[t - off] : 0;
        __syncthreads();
        ps[t] += add;
        __syncthreads();
    }
    int run = ps[t] - s + beg;
    __syncthreads();
    int k = key0 + 4 * t;
    if (k + 0 < M) rowptr[k + 0] = run; h[4 * t + 0] = run; run += v0;
    if (k + 1 < M) rowptr[k + 1] = run; h[4 * t + 1] = run; run += v1;
    if (k + 2 < M) rowptr[k + 2] = run; h[4 * t + 2] = run; run += v2;
    if (k + 3 < M) rowptr[k + 3] = run; h[4 * t + 3] = run;
    __syncthreads();
    for (int p = beg + t; p < end; p += 256) {
        int2 pr = pairs[p];
        int slot = atomicAdd(&h[pr.x - key0], 1);
        col[slot] = pr.y;
    }
}

// ---- gather-mean: 8 lanes/node, 32B/lane, unroll-4, bf16 in/out ----
__global__ __launch_bounds__(256) void k_gather_mean(
        const ushort* __restrict__ xib, const ushort* __restrict__ xtb,
        const int* __restrict__ rowptr, const int* __restrict__ col,
        ushort* __restrict__ mi, ushort* __restrict__ mt, int N) {
    int t = blockIdx.x * 256 + threadIdx.x;
    int node = t >> 3, lane = t & 7;
    if (node >= N) return;
    int rel = blockIdx.y;
    const ushort* xs = rel ? xtb : xib;
    ushort* mean = rel ? mt : mi;
    const int c0 = lane * 16;
    int rb = rel * N + node;
    int beg = rowptr[rb], end = rowptr[rb + 1];
    float a[16];
    #pragma unroll
    for (int q = 0; q < 16; ++q) a[q] = 0.f;
    int j = beg;
    for (; j + 3 < end; j += 4) {
        int s0 = col[j], s1 = col[j + 1], s2 = col[j + 2], s3 = col[j + 3];
        const ushort* r0 = xs + (size_t)s0 * 128 + c0;
        const ushort* r1 = xs + (size_t)s1 * 128 + c0;
        const ushort* r2 = xs + (size_t)s2 * 128 + c0;
        const ushort* r3 = xs + (size_t)s3 * 128 + c0;
        u16x8 v0a = *reinterpret_cast<const u16x8*>(r0);
        u16x8 v0b = *reinterpret_cast<const u16x8*>(r0 + 8);
        u16x8 v1a = *reinterpret_cast<const u16x8*>(r1);
        u16x8 v1b = *reinterpret_cast<const u16x8*>(r1 + 8);
        u16x8 v2a = *reinterpret_cast<const u16x8*>(r2);
        u16x8 v2b = *reinterpret_cast<const u16x8*>(r2 + 8);
        u16x8 v3a = *reinterpret_cast<const u16x8*>(r3);
        u16x8 v3b = *reinterpret_cast<const u16x8*>(r3 + 8);
        #pragma unroll
        for (int q = 0; q < 8; ++q) {
            a[q]     += (b2f(v0a[q]) + b2f(v1a[q])) + (b2f(v2a[q]) + b2f(v3a[q]));
            a[q + 8] += (b2f(v0b[q]) + b2f(v1b[q])) + (b2f(v2b[q]) + b2f(v3b[q]));
        }
    }
    for (; j < end; ++j) {
        const ushort* r0 = xs + (size_t)col[j] * 128 + c0;
        u16x8 v0a = *reinterpret_cast<const u16x8*>(r0);
        u16x8 v0b = *reinterpret_cast<const u16x8*>(r0 + 8);
        #pragma unroll
        for (int q = 0; q < 8; ++q) { a[q] += b2f(v0a[q]); a[q + 8] += b2f(v0b[q]); }
    }
    float r = (end > beg) ? 1.0f / (float)(end - beg) : 0.0f;
    u16x8 o0, o1;
    #pragma unroll
    for (int q = 0; q < 8; ++q) { o0[q] = f2b(a[q] * r); o1[q] = f2b(a[q + 8] * r); }
    *reinterpret_cast<u16x8*>(mean + (size_t)node * 128 + c0) = o0;
    *reinterpret_cast<u16x8*>(mean + (size_t)node * 128 + c0 + 8) = o1;
}

// ---- out = relu( [mi|mt|x_user](K=512) @ Bp + bias ) : MFMA, B in LDS ----
// 256 thr / 4 waves / 128 rows per block; B staged in 4x32KB quarters.
__global__ __launch_bounds__(256) void k_final_mfma(
        const ushort* __restrict__ mi, const ushort* __restrict__ mt,
        const float* __restrict__ x_user, const ushort* __restrict__ Bp,
        const float* __restrict__ bias, float* __restrict__ out, int N) {
    __shared__ u16x8 bl8[2048];                  // 32 KB quarter of B
    const int tid = threadIdx.x;
    const int wid = tid >> 6, lane = tid & 63;
    const int r0g = blockIdx.x * 128 + wid * 32 + (lane & 15);
    const int rA0 = min(r0g, N - 1);
    const int rA1 = min(r0g + 16, N - 1);
    const int kh = (lane >> 4) * 8;
    f32x4 acc0[8] = {}, acc1[8] = {};

    const u16x8* Bp8 = reinterpret_cast<const u16x8*>(Bp);

    #pragma unroll
    for (int qt = 0; qt < 4; ++qt) {
        // ---- stage 32KB quarter of B (ks = qt*4 .. qt*4+3) ----
        __syncthreads();                         // protect previous quarter's reads
        #pragma unroll
        for (int it = 0; it < 8; ++it)
            bl8[it * 256 + tid] = Bp8[qt * 2048 + it * 256 + tid];
        __syncthreads();

        if (qt < 2) {
            // ---- A from mi (qt=0) / mt (qt=1) ----
            const ushort* s = qt ? mt : mi;
            #pragma unroll
            for (int kk = 0; kk < 4; ++kk) {
                bf16x8 a0 = *reinterpret_cast<const bf16x8*>(s + (size_t)rA0 * 128 + kk * 32 + kh);
                bf16x8 a1 = *reinterpret_cast<const bf16x8*>(s + (size_t)rA1 * 128 + kk * 32 + kh);
                #pragma unroll
                for (int cf = 0; cf < 8; ++cf) {
                    bf16x8 bb = *reinterpret_cast<const bf16x8*>(&bl8[(kk * 8 + cf) * 64 + lane]);
                    acc0[cf] = __builtin_amdgcn_mfma_f32_16x16x32_bf16(a0, bb, acc0[cf], 0, 0, 0);
                    acc1[cf] = __builtin_amdgcn_mfma_f32_16x16x32_bf16(a1, bb, acc1[cf], 0, 0, 0);
                }
            }
        } else {
            // ---- A from x_user (f32, inline cvt); ks global 8..15 ----
            const float* Xr0 = x_user + (size_t)rA0 * 256 + (qt - 2) * 128;
            const float* Xr1 = x_user + (size_t)rA1 * 256 + (qt - 2) * 128;
            #pragma unroll
            for (int kk = 0; kk < 4; ++kk) {
                int k0 = kk * 32 + kh;
                float4 f0 = *reinterpret_cast<const float4*>(Xr0 + k0);
                float4 f1 = *reinterpret_cast<const float4*>(Xr0 + k0 + 4);
                float4 g0 = *reinterpret_cast<const float4*>(Xr1 + k0);
                float4 g1 = *reinterpret_cast<const float4*>(Xr1 + k0 + 4);
                bf16x8 a0, a1;
                a0[0] = (short)f2b(f0.x); a0[1] = (short)f2b(f0.y);
                a0[2] = (short)f2b(f0.z); a0[3] = (short)f2b(f0.w);
                a0[4] = (short)f2b(f1.x); a0[5] = (short)f2b(f1.y);
                a0[6] = (short)f2b(f1.z); a0[7] = (short)f2b(f1.w);
                a1[0] = (short)f2b(g0.x); a1[1] = (short)f2b(g0.y);
                a1[2] = (short)f2b(g0.z); a1[3] = (short)f2b(g0.w);
                a1[4] = (short)f2b(g1.x); a1[5] = (short)f2b(g1.y);
                a1[6] = (short)f2b(g1.z); a1[7] = (short)f2b(g1.w);
                #pragma unroll
                for (int cf = 0; cf < 8; ++cf) {
                    bf16x8 bb = *reinterpret_cast<const bf16x8*>(&bl8[(kk * 8 + cf) * 64 + lane]);
                    acc0[cf] = __builtin_amdgcn_mfma_f32_16x16x32_bf16(a0, bb, acc0[cf], 0, 0, 0);
                    acc1[cf] = __builtin_amdgcn_mfma_f32_16x16x32_bf16(a1, bb, acc1[cf], 0, 0, 0);
                }
            }
        }
    }

    // ---- epilogue: bias + relu + store (2 row groups) ----
    const int col0 = lane & 15;
    const int rbase = blockIdx.x * 128 + wid * 32 + (lane >> 4) * 4;
    #pragma unroll
    for (int cf = 0; cf < 8; ++cf) {
        int c = cf * 16 + col0;
        float bv = bias[c];
        #pragma unroll
        for (int r = 0; r < 4; ++r) {
            int row = rbase + r;
            if (row < N) out[(size_t)row * 128 + c] = fmaxf(acc0[cf][r] + bv, 0.f);
            int row2 = rbase + 16 + r;
            if (row2 < N) out[(size_t)row2 * 128 + c] = fmaxf(acc1[cf][r] + bv, 0.f);
        }
    }
}

extern "C" void kernel_launch(void* const* d_in, const int* in_sizes, int n_in,
                              void* d_out, int out_size, void* d_ws, size_t ws_size,
                              hipStream_t stream) {
    const float* x_user  = (const float*)d_in[0];
    const float* x_image = (const float*)d_in[1];
    const float* x_text  = (const float*)d_in[2];
    const int*   edge_i  = (const int*)d_in[3];
    const int*   edge_t  = (const int*)d_in[4];
    const float* W_user  = (const float*)d_in[5];
    const float* b_user  = (const float*)d_in[6];
    const float* Wl_img  = (const float*)d_in[7];
    const float* bl_img  = (const float*)d_in[8];
    const float* Wr_img  = (const float*)d_in[9];
    const float* Wl_txt  = (const float*)d_in[10];
    const float* bl_txt  = (const float*)d_in[11];
    const float* Wr_txt  = (const float*)d_in[12];

    const int N = in_sizes[0] / 256;   // 100000 nodes per type
    const int E = in_sizes[3] / 2;     // 800000 edges per relation
    const int M = 2 * N;
    const int nblkR = (E + BK - 1) / BK;           // 196
    const int NBLK = 2 * nblkR;                    // 392 (<=512 for k_s1)
    const int nbuk = (M + 1023) >> 10;             // 196 (<=MAXBUK)

    ushort* xib    = (ushort*)d_ws;                // N*128
    ushort* xtb    = xib + (size_t)N * 128;        // N*128
    ushort* mi     = xtb + (size_t)N * 128;        // N*128
    ushort* mt     = mi  + (size_t)N * 128;        // N*128
    ushort* Bp     = mt  + (size_t)N * 128;        // 65536
    float*  bias   = (float*)(Bp + 65536);         // 128
    int*    counts = (int*)(bias + 128);           // NBLK*nbuk
    int*    T      = counts + (size_t)NBLK * nbuk; // 256
    int*    Bb     = T + 256;                      // nbuk+1 (pad 260)
    int*    rowptr = Bb + 260;                     // M+4
    int*    col    = rowptr + (M + 4);             // 2E
    int2*   pairs  = (int2*)(col + (size_t)2 * E); // 2E int2

    const int nbC = (2 * N * 16 + 255) / 256;      // convert blocks
    const int nbP = 256;                           // pack blocks (65536 thr)
    k_front<<<NBLK + nbC + nbP, 256, 0, stream>>>(
        x_image, x_text, edge_i, edge_t,
        Wl_img, Wl_txt, W_user, b_user, Wr_img, Wr_txt, bl_img, bl_txt,
        xib, xtb, Bp, bias, counts, N, E, nblkR, nbuk, nbC);

    k_s1<<<nbuk, 256, 0, stream>>>(counts, T, NBLK, nbuk);
    k_s2<<<1, 256, 0, stream>>>(T, Bb, rowptr, M, 2 * E, nbuk);
    k_part1<<<NBLK, 256, 0, stream>>>(edge_i, edge_t, counts, Bb, pairs,
                                      N, E, nblkR, nbuk);
    k_part2<<<nbuk, 256, 0, stream>>>(pairs, Bb, rowptr, col, M);

    {
        dim3 g((N * 8 + 255) / 256, 2);
        k_gather_mean<<<g, 256, 0, stream>>>(xib, xtb, rowptr, col, mi, mt, N);
    }

    k_final_mfma<<<(N + 127) / 128, 256, 0, stream>>>(
        mi, mt, x_user, Bp, bias, (float*)d_out, N);
}

// Round 12
// 215.026 us; speedup vs baseline: 1.0574x; 1.0574x over previous
//
#include <hip/hip_runtime.h>

// ---------------------------------------------------------------------------
// HeteroGNN, round 12: revert final GEMM to r10 structure (512thr/256rows/
// 2x64KB halves — r11's 4-quarter version regressed: barrier-serialized
// staging + 19% occupancy). Keep r11 gather (8 lanes/node) + pack fusion.
// New: x_user converted to bf16 in front pass -> final reads bf16 A only.
//   out = relu( [mean_i | mean_t | x_user] @ [Wl_i; Wl_t; W_user@(Wr_i+Wr_t)]
//               + (b_user@(Wr_i+Wr_t) + bl_i + bl_t) )        [MFMA, K=512]
// CSR: two-level bucket partition, zero global atomics (r9).
// MFMA 16x16x32_bf16: A row=lane&15, k=(lane>>4)*8+j; B col=lane&15;
// D col=lane&15, row=(lane>>4)*4+reg  [m89-verified].
// ---------------------------------------------------------------------------

#define BK 4096          // edges per level-1 block
#define MAXBUK 256       // >= nbuk = ceil(2N/1024) = 196

typedef __attribute__((ext_vector_type(8))) short bf16x8;
typedef __attribute__((ext_vector_type(8))) unsigned short u16x8;
typedef __attribute__((ext_vector_type(4))) float f32x4;

__device__ __forceinline__ ushort f2b(float x) {
    union { float f; unsigned u; } v; v.f = x;
    unsigned r = (v.u + 0x7FFF + ((v.u >> 16) & 1)) >> 16;   // RNE
    return (ushort)r;
}
__device__ __forceinline__ float b2f(ushort u) {
    union { unsigned u; float f; } v; v.u = (unsigned)u << 16;
    return v.f;
}

// ---- fused front: [bucket hist (LDS) | bf16 convert (img/txt/user) | pack] ----
__global__ __launch_bounds__(256) void k_front(
        const float* __restrict__ x_image, const float* __restrict__ x_text,
        const float* __restrict__ x_user,
        const int* __restrict__ edge_i, const int* __restrict__ edge_t,
        const float* __restrict__ Wl_i, const float* __restrict__ Wl_t,
        const float* __restrict__ W_user, const float* __restrict__ b_user,
        const float* __restrict__ Wr_i, const float* __restrict__ Wr_t,
        const float* __restrict__ bl_i, const float* __restrict__ bl_t,
        ushort* __restrict__ xib, ushort* __restrict__ xtb,
        ushort* __restrict__ xub,
        ushort* __restrict__ Bp, float* __restrict__ bias,
        int* __restrict__ counts,
        int N, int E, int nblkR, int nbuk, int nbC) {
    __shared__ int h[MAXBUK];
    const int bid = blockIdx.x;
    const int tid = threadIdx.x;
    const int NBLK = 2 * nblkR;

    if (bid < NBLK) {
        // ---- level-1 histogram of bucket = key>>10, LDS atomics only ----
        int rel = (bid >= nblkR) ? 1 : 0;
        int blk = bid - rel * nblkR;
        const int* eg = rel ? edge_t : edge_i;
        const int relN = rel * N;
        for (int i = tid; i < nbuk; i += 256) h[i] = 0;
        __syncthreads();
        int base = blk * BK;
        #pragma unroll
        for (int j = 0; j < 4; ++j) {
            int e = base + (j * 256 + tid) * 4;
            if (e + 3 < E) {
                int4 d4 = *reinterpret_cast<const int4*>(eg + E + e);
                atomicAdd(&h[(relN + d4.x) >> 10], 1);
                atomicAdd(&h[(relN + d4.y) >> 10], 1);
                atomicAdd(&h[(relN + d4.z) >> 10], 1);
                atomicAdd(&h[(relN + d4.w) >> 10], 1);
            } else {
                for (int q = 0; q < 4; ++q) {
                    int ee = e + q;
                    if (ee < E) atomicAdd(&h[(relN + eg[E + ee]) >> 10], 1);
                }
            }
        }
        __syncthreads();
        for (int i = tid; i < nbuk; i += 256) counts[(size_t)bid * nbuk + i] = h[i];
    } else if (bid < NBLK + nbC) {
        // ---- f32 -> bf16: image (N*16 grp), text (N*16), user (N*32) ----
        int t = (bid - NBLK) * 256 + tid;
        int n8 = N * 16;
        if (t >= 4 * n8) return;                 // total N*64 groups of 8
        const float* src; ushort* dst; int i;
        if (t < n8)          { src = x_image; dst = xib; i = t; }
        else if (t < 2 * n8) { src = x_text;  dst = xtb; i = t - n8; }
        else                 { src = x_user;  dst = xub; i = t - 2 * n8; }
        float4 f0 = *reinterpret_cast<const float4*>(src + (size_t)i * 8);
        float4 f1 = *reinterpret_cast<const float4*>(src + (size_t)i * 8 + 4);
        u16x8 o;
        o[0] = f2b(f0.x); o[1] = f2b(f0.y); o[2] = f2b(f0.z); o[3] = f2b(f0.w);
        o[4] = f2b(f1.x); o[5] = f2b(f1.y); o[6] = f2b(f1.z); o[7] = f2b(f1.w);
        *reinterpret_cast<u16x8*>(dst + (size_t)i * 8) = o;
    } else {
        // ---- pack Bp [512x128] = [Wl_i; Wl_t; W_user@(Wr_i+Wr_t)] + bias ----
        int i = (bid - NBLK - nbC) * 256 + tid;      // < 65536
        int j = i & 7, lane = (i >> 3) & 63, cf = (i >> 9) & 7, ks = i >> 12;
        int kk = ks * 32 + (lane >> 4) * 8 + j;
        int col = cf * 16 + (lane & 15);
        float v;
        if (kk < 128)      v = Wl_i[kk * 128 + col];
        else if (kk < 256) v = Wl_t[(kk - 128) * 128 + col];
        else {
            int k2 = kk - 256;
            float s = 0.f;
            for (int c1 = 0; c1 < 128; ++c1)
                s += W_user[k2 * 128 + c1] * (Wr_i[c1 * 128 + col] + Wr_t[c1 * 128 + col]);
            v = s;
        }
        Bp[i] = f2b(v);
        if (i < 128) {
            float b = bl_i[i] + bl_t[i];
            for (int k2 = 0; k2 < 128; ++k2)
                b += b_user[k2] * (Wr_i[k2 * 128 + i] + Wr_t[k2 * 128 + i]);
            bias[i] = b;
        }
    }
}

// ---- s1: per-bucket exclusive prefix over blocks (in-place) + totals ----
__global__ __launch_bounds__(256) void k_s1(int* __restrict__ counts,
                                            int* __restrict__ T,
                                            int NBLK, int nbuk) {
    __shared__ int a[512];
    __shared__ int ps[256];
    const int b = blockIdx.x, t = threadIdx.x;
    a[t]       = (t < NBLK)       ? counts[(size_t)t * nbuk + b] : 0;
    a[t + 256] = (t + 256 < NBLK) ? counts[(size_t)(t + 256) * nbuk + b] : 0;
    __syncthreads();
    int x0 = a[2 * t], x1 = a[2 * t + 1];
    int s = x0 + x1;
    ps[t] = s; __syncthreads();
    for (int off = 1; off < 256; off <<= 1) {
        int add = (t >= off) ? ps[t - off] : 0;
        __syncthreads();
        ps[t] += add;
        __syncthreads();
    }
    int ex = ps[t] - s;
    if (2 * t < NBLK)     counts[(size_t)(2 * t) * nbuk + b] = ex;
    if (2 * t + 1 < NBLK) counts[(size_t)(2 * t + 1) * nbuk + b] = ex + x0;
    if (t == 255) T[b] = ps[255];
}

// ---- s2: exclusive scan of bucket totals -> bucket bases ----
__global__ __launch_bounds__(256) void k_s2(const int* __restrict__ T,
                                            int* __restrict__ Bb,
                                            int* __restrict__ rowptr,
                                            int M, int Etot, int nbuk) {
    __shared__ int sh[256];
    int t = threadIdx.x;
    int v = (t < nbuk) ? T[t] : 0;
    sh[t] = v; __syncthreads();
    for (int off = 1; off < 256; off <<= 1) {
        int add = (t >= off) ? sh[t - off] : 0;
        __syncthreads();
        sh[t] += add;
        __syncthreads();
    }
    if (t < nbuk) Bb[t] = sh[t] - v;
    if (t == 0) { Bb[nbuk] = Etot; rowptr[M] = Etot; }
}

// ---- part1: scatter (key,src) pairs into bucket regions via LDS cursors ----
__global__ __launch_bounds__(256) void k_part1(
        const int* __restrict__ edge_i, const int* __restrict__ edge_t,
        const int* __restrict__ counts, const int* __restrict__ Bb,
        int2* __restrict__ pairs, int N, int E, int nblkR, int nbuk) {
    __shared__ int cur[MAXBUK];
    const int bid = blockIdx.x, tid = threadIdx.x;
    int rel = (bid >= nblkR) ? 1 : 0;
    int blk = bid - rel * nblkR;
    const int* eg = rel ? edge_t : edge_i;
    const int relN = rel * N;
    for (int i = tid; i < nbuk; i += 256)
        cur[i] = Bb[i] + counts[(size_t)bid * nbuk + i];
    __syncthreads();
    int base = blk * BK;
    #pragma unroll
    for (int j = 0; j < 4; ++j) {
        int e = base + (j * 256 + tid) * 4;
        if (e + 3 < E) {
            int4 d4 = *reinterpret_cast<const int4*>(eg + E + e);
            int4 s4 = *reinterpret_cast<const int4*>(eg + e);
            int k0 = relN + d4.x, k1 = relN + d4.y, k2 = relN + d4.z, k3 = relN + d4.w;
            int p0 = atomicAdd(&cur[k0 >> 10], 1); pairs[p0] = make_int2(k0, s4.x);
            int p1 = atomicAdd(&cur[k1 >> 10], 1); pairs[p1] = make_int2(k1, s4.y);
            int p2 = atomicAdd(&cur[k2 >> 10], 1); pairs[p2] = make_int2(k2, s4.z);
            int p3 = atomicAdd(&cur[k3 >> 10], 1); pairs[p3] = make_int2(k3, s4.w);
        } else {
            for (int q = 0; q < 4; ++q) {
                int ee = e + q;
                if (ee < E) {
                    int k0 = relN + eg[E + ee];
                    int p0 = atomicAdd(&cur[k0 >> 10], 1);
                    pairs[p0] = make_int2(k0, eg[ee]);
                }
            }
        }
    }
}

// ---- part2: per-bucket (1024 keys) hist/scan -> rowptr + col ----
__global__ __launch_bounds__(256) void k_part2(
        const int2* __restrict__ pairs, const int* __restrict__ Bb,
        int* __restrict__ rowptr, int* __restrict__ col, int M) {
    __shared__ int h[1024];
    __shared__ int ps[256];
    const int b = blockIdx.x, t = threadIdx.x;
    const int key0 = b << 10;
    const int beg = Bb[b], end = Bb[b + 1];
    for (int i = t; i < 1024; i += 256) h[i] = 0;
    __syncthreads();
    for (int p = beg + t; p < end; p += 256)
        atomicAdd(&h[pairs[p].x - key0], 1);
    __syncthreads();
    int v0 = h[4 * t], v1 = h[4 * t + 1], v2 = h[4 * t + 2], v3 = h[4 * t + 3];
    int s = v0 + v1 + v2 + v3;
    ps[t] = s; __syncthreads();
    for (int off = 1; off < 256; off <<= 1) {
        int add = (t >= off) ? ps[t - off] : 0;
        __syncthreads();
        ps[t] += add;
        __syncthreads();
    }
    int run = ps[t] - s + beg;
    __syncthreads();
    int k = key0 + 4 * t;
    if (k + 0 < M) rowptr[k + 0] = run; h[4 * t + 0] = run; run += v0;
    if (k + 1 < M) rowptr[k + 1] = run; h[4 * t + 1] = run; run += v1;
    if (k + 2 < M) rowptr[k + 2] = run; h[4 * t + 2] = run; run += v2;
    if (k + 3 < M) rowptr[k + 3] = run; h[4 * t + 3] = run;
    __syncthreads();
    for (int p = beg + t; p < end; p += 256) {
        int2 pr = pairs[p];
        int slot = atomicAdd(&h[pr.x - key0], 1);
        col[slot] = pr.y;
    }
}

// ---- gather-mean: 8 lanes/node, 32B/lane, unroll-4, bf16 in/out ----
__global__ __launch_bounds__(256) void k_gather_mean(
        const ushort* __restrict__ xib, const ushort* __restrict__ xtb,
        const int* __restrict__ rowptr, const int* __restrict__ col,
        ushort* __restrict__ mi, ushort* __restrict__ mt, int N) {
    int t = blockIdx.x * 256 + threadIdx.x;
    int node = t >> 3, lane = t & 7;
    if (node >= N) return;
    int rel = blockIdx.y;
    const ushort* xs = rel ? xtb : xib;
    ushort* mean = rel ? mt : mi;
    const int c0 = lane * 16;
    int rb = rel * N + node;
    int beg = rowptr[rb], end = rowptr[rb + 1];
    float a[16];
    #pragma unroll
    for (int q = 0; q < 16; ++q) a[q] = 0.f;
    int j = beg;
    for (; j + 3 < end; j += 4) {
        int s0 = col[j], s1 = col[j + 1], s2 = col[j + 2], s3 = col[j + 3];
        const ushort* r0 = xs + (size_t)s0 * 128 + c0;
        const ushort* r1 = xs + (size_t)s1 * 128 + c0;
        const ushort* r2 = xs + (size_t)s2 * 128 + c0;
        const ushort* r3 = xs + (size_t)s3 * 128 + c0;
        u16x8 v0a = *reinterpret_cast<const u16x8*>(r0);
        u16x8 v0b = *reinterpret_cast<const u16x8*>(r0 + 8);
        u16x8 v1a = *reinterpret_cast<const u16x8*>(r1);
        u16x8 v1b = *reinterpret_cast<const u16x8*>(r1 + 8);
        u16x8 v2a = *reinterpret_cast<const u16x8*>(r2);
        u16x8 v2b = *reinterpret_cast<const u16x8*>(r2 + 8);
        u16x8 v3a = *reinterpret_cast<const u16x8*>(r3);
        u16x8 v3b = *reinterpret_cast<const u16x8*>(r3 + 8);
        #pragma unroll
        for (int q = 0; q < 8; ++q) {
            a[q]     += (b2f(v0a[q]) + b2f(v1a[q])) + (b2f(v2a[q]) + b2f(v3a[q]));
            a[q + 8] += (b2f(v0b[q]) + b2f(v1b[q])) + (b2f(v2b[q]) + b2f(v3b[q]));
        }
    }
    for (; j < end; ++j) {
        const ushort* r0 = xs + (size_t)col[j] * 128 + c0;
        u16x8 v0a = *reinterpret_cast<const u16x8*>(r0);
        u16x8 v0b = *reinterpret_cast<const u16x8*>(r0 + 8);
        #pragma unroll
        for (int q = 0; q < 8; ++q) { a[q] += b2f(v0a[q]); a[q + 8] += b2f(v0b[q]); }
    }
    float r = (end > beg) ? 1.0f / (float)(end - beg) : 0.0f;
    u16x8 o0, o1;
    #pragma unroll
    for (int q = 0; q < 8; ++q) { o0[q] = f2b(a[q] * r); o1[q] = f2b(a[q + 8] * r); }
    *reinterpret_cast<u16x8*>(mean + (size_t)node * 128 + c0) = o0;
    *reinterpret_cast<u16x8*>(mean + (size_t)node * 128 + c0 + 8) = o1;
}

// ---- out = relu( [mi|mt|xub](K=512) @ Bp + bias ) : MFMA, B in LDS ----
// 512 thr / 8 waves, 256 rows per block (32 rows/wave), B staged in 2x64KB.
__global__ __launch_bounds__(512) void k_final_mfma(
        const ushort* __restrict__ mi, const ushort* __restrict__ mt,
        const ushort* __restrict__ xub, const ushort* __restrict__ Bp,
        const float* __restrict__ bias, float* __restrict__ out, int N) {
    __shared__ u16x8 bl8[4096];                  // 64 KB half of B
    const int tid = threadIdx.x;
    const int wid = tid >> 6, lane = tid & 63;
    const int r0g = blockIdx.x * 256 + wid * 32 + (lane & 15);
    const int rA0 = min(r0g, N - 1);
    const int rA1 = min(r0g + 16, N - 1);
    const int kh = (lane >> 4) * 8;
    f32x4 acc0[8] = {}, acc1[8] = {};

    const u16x8* Bp8 = reinterpret_cast<const u16x8*>(Bp);

    #pragma unroll
    for (int h = 0; h < 2; ++h) {
        // ---- stage 64KB half of B into LDS (linear copy) ----
        if (h) __syncthreads();                  // protect previous half's reads
        #pragma unroll
        for (int it = 0; it < 8; ++it)
            bl8[it * 512 + tid] = Bp8[h * 4096 + it * 512 + tid];
        __syncthreads();

        if (h == 0) {
            // ---- ks 0..7: A from mi/mt (bf16) ----
            #pragma unroll
            for (int ks = 0; ks < 8; ++ks) {
                const ushort* s = (ks < 4) ? mi : mt;
                bf16x8 a0 = *reinterpret_cast<const bf16x8*>(s + (size_t)rA0 * 128 + (ks & 3) * 32 + kh);
                bf16x8 a1 = *reinterpret_cast<const bf16x8*>(s + (size_t)rA1 * 128 + (ks & 3) * 32 + kh);
                #pragma unroll
                for (int cf = 0; cf < 8; ++cf) {
                    bf16x8 bb = *reinterpret_cast<const bf16x8*>(&bl8[(ks * 8 + cf) * 64 + lane]);
                    acc0[cf] = __builtin_amdgcn_mfma_f32_16x16x32_bf16(a0, bb, acc0[cf], 0, 0, 0);
                    acc1[cf] = __builtin_amdgcn_mfma_f32_16x16x32_bf16(a1, bb, acc1[cf], 0, 0, 0);
                }
            }
        } else {
            // ---- ks 8..15: A from xub (bf16, stride 256) ----
            const ushort* Xr0 = xub + (size_t)rA0 * 256;
            const ushort* Xr1 = xub + (size_t)rA1 * 256;
            #pragma unroll
            for (int ks = 0; ks < 8; ++ks) {
                bf16x8 a0 = *reinterpret_cast<const bf16x8*>(Xr0 + ks * 32 + kh);
                bf16x8 a1 = *reinterpret_cast<const bf16x8*>(Xr1 + ks * 32 + kh);
                #pragma unroll
                for (int cf = 0; cf < 8; ++cf) {
                    bf16x8 bb = *reinterpret_cast<const bf16x8*>(&bl8[(ks * 8 + cf) * 64 + lane]);
                    acc0[cf] = __builtin_amdgcn_mfma_f32_16x16x32_bf16(a0, bb, acc0[cf], 0, 0, 0);
                    acc1[cf] = __builtin_amdgcn_mfma_f32_16x16x32_bf16(a1, bb, acc1[cf], 0, 0, 0);
                }
            }
        }
    }

    // ---- epilogue: bias + relu + store (2 row groups) ----
    const int col0 = lane & 15;
    const int rbase = blockIdx.x * 256 + wid * 32 + (lane >> 4) * 4;
    #pragma unroll
    for (int cf = 0; cf < 8; ++cf) {
        int c = cf * 16 + col0;
        float bv = bias[c];
        #pragma unroll
        for (int r = 0; r < 4; ++r) {
            int row = rbase + r;
            if (row < N) out[(size_t)row * 128 + c] = fmaxf(acc0[cf][r] + bv, 0.f);
            int row2 = rbase + 16 + r;
            if (row2 < N) out[(size_t)row2 * 128 + c] = fmaxf(acc1[cf][r] + bv, 0.f);
        }
    }
}

extern "C" void kernel_launch(void* const* d_in, const int* in_sizes, int n_in,
                              void* d_out, int out_size, void* d_ws, size_t ws_size,
                              hipStream_t stream) {
    const float* x_user  = (const float*)d_in[0];
    const float* x_image = (const float*)d_in[1];
    const float* x_text  = (const float*)d_in[2];
    const int*   edge_i  = (const int*)d_in[3];
    const int*   edge_t  = (const int*)d_in[4];
    const float* W_user  = (const float*)d_in[5];
    const float* b_user  = (const float*)d_in[6];
    const float* Wl_img  = (const float*)d_in[7];
    const float* bl_img  = (const float*)d_in[8];
    const float* Wr_img  = (const float*)d_in[9];
    const float* Wl_txt  = (const float*)d_in[10];
    const float* bl_txt  = (const float*)d_in[11];
    const float* Wr_txt  = (const float*)d_in[12];

    const int N = in_sizes[0] / 256;   // 100000 nodes per type
    const int E = in_sizes[3] / 2;     // 800000 edges per relation
    const int M = 2 * N;
    const int nblkR = (E + BK - 1) / BK;           // 196
    const int NBLK = 2 * nblkR;                    // 392 (<=512 for k_s1)
    const int nbuk = (M + 1023) >> 10;             // 196 (<=MAXBUK)

    ushort* xib    = (ushort*)d_ws;                // N*128
    ushort* xtb    = xib + (size_t)N * 128;        // N*128
    ushort* xub    = xtb + (size_t)N * 128;        // N*256
    ushort* mi     = xub + (size_t)N * 256;        // N*128
    ushort* mt     = mi  + (size_t)N * 128;        // N*128
    ushort* Bp     = mt  + (size_t)N * 128;        // 65536
    float*  bias   = (float*)(Bp + 65536);         // 128
    int*    counts = (int*)(bias + 128);           // NBLK*nbuk
    int*    T      = counts + (size_t)NBLK * nbuk; // 256
    int*    Bb     = T + 256;                      // nbuk+1 (pad 260)
    int*    rowptr = Bb + 260;                     // M+4
    int*    col    = rowptr + (M + 4);             // 2E
    int2*   pairs  = (int2*)(col + (size_t)2 * E); // 2E int2

    const int nbC = (4 * N * 16 + 255) / 256;      // convert blocks (img+txt+user)
    const int nbP = 256;                           // pack blocks (65536 thr)
    k_front<<<NBLK + nbC + nbP, 256, 0, stream>>>(
        x_image, x_text, x_user, edge_i, edge_t,
        Wl_img, Wl_txt, W_user, b_user, Wr_img, Wr_txt, bl_img, bl_txt,
        xib, xtb, xub, Bp, bias, counts, N, E, nblkR, nbuk, nbC);

    k_s1<<<nbuk, 256, 0, stream>>>(counts, T, NBLK, nbuk);
    k_s2<<<1, 256, 0, stream>>>(T, Bb, rowptr, M, 2 * E, nbuk);
    k_part1<<<NBLK, 256, 0, stream>>>(edge_i, edge_t, counts, Bb, pairs,
                                      N, E, nblkR, nbuk);
    k_part2<<<nbuk, 256, 0, stream>>>(pairs, Bb, rowptr, col, M);

    {
        dim3 g((N * 8 + 255) / 256, 2);
        k_gather_mean<<<g, 256, 0, stream>>>(xib, xtb, rowptr, col, mi, mt, N);
    }

    k_final_mfma<<<(N + 255) / 256, 512, 0, stream>>>(
        mi, mt, xub, Bp, bias, (float*)d_out, N);
}

// Round 13
// 199.809 us; speedup vs baseline: 1.1379x; 1.0762x over previous
//
#include <hip/hip_runtime.h>

// ---------------------------------------------------------------------------
// HeteroGNN, round 13: best-measured combination.
//   front = hist + img/txt bf16 convert + weight pack (r11, no user convert)
//   gather = 8 lanes/node, 32B/lane, unroll-4 (r11)
//   final = 512thr/256rows, 2x64KB LDS B-halves, x_user f32 inline cvt (r10)
//   out = relu( [mean_i | mean_t | x_user] @ [Wl_i; Wl_t; W_user@(Wr_i+Wr_t)]
//               + (b_user@(Wr_i+Wr_t) + bl_i + bl_t) )        [MFMA, K=512]
// CSR: two-level bucket partition, zero global atomics (r9).
// MFMA 16x16x32_bf16: A row=lane&15, k=(lane>>4)*8+j; B col=lane&15;
// D col=lane&15, row=(lane>>4)*4+reg  [m89-verified].
// ---------------------------------------------------------------------------

#define BK 4096          // edges per level-1 block
#define MAXBUK 256       // >= nbuk = ceil(2N/1024) = 196

typedef __attribute__((ext_vector_type(8))) short bf16x8;
typedef __attribute__((ext_vector_type(8))) unsigned short u16x8;
typedef __attribute__((ext_vector_type(4))) float f32x4;

__device__ __forceinline__ ushort f2b(float x) {
    union { float f; unsigned u; } v; v.f = x;
    unsigned r = (v.u + 0x7FFF + ((v.u >> 16) & 1)) >> 16;   // RNE
    return (ushort)r;
}
__device__ __forceinline__ float b2f(ushort u) {
    union { unsigned u; float f; } v; v.u = (unsigned)u << 16;
    return v.f;
}

// ---- fused front: [bucket hist (LDS) | bf16 convert (img/txt) | pack] ----
__global__ __launch_bounds__(256) void k_front(
        const float* __restrict__ x_image, const float* __restrict__ x_text,
        const int* __restrict__ edge_i, const int* __restrict__ edge_t,
        const float* __restrict__ Wl_i, const float* __restrict__ Wl_t,
        const float* __restrict__ W_user, const float* __restrict__ b_user,
        const float* __restrict__ Wr_i, const float* __restrict__ Wr_t,
        const float* __restrict__ bl_i, const float* __restrict__ bl_t,
        ushort* __restrict__ xib, ushort* __restrict__ xtb,
        ushort* __restrict__ Bp, float* __restrict__ bias,
        int* __restrict__ counts,
        int N, int E, int nblkR, int nbuk, int nbC) {
    __shared__ int h[MAXBUK];
    const int bid = blockIdx.x;
    const int tid = threadIdx.x;
    const int NBLK = 2 * nblkR;

    if (bid < NBLK) {
        // ---- level-1 histogram of bucket = key>>10, LDS atomics only ----
        int rel = (bid >= nblkR) ? 1 : 0;
        int blk = bid - rel * nblkR;
        const int* eg = rel ? edge_t : edge_i;
        const int relN = rel * N;
        for (int i = tid; i < nbuk; i += 256) h[i] = 0;
        __syncthreads();
        int base = blk * BK;
        #pragma unroll
        for (int j = 0; j < 4; ++j) {
            int e = base + (j * 256 + tid) * 4;
            if (e + 3 < E) {
                int4 d4 = *reinterpret_cast<const int4*>(eg + E + e);
                atomicAdd(&h[(relN + d4.x) >> 10], 1);
                atomicAdd(&h[(relN + d4.y) >> 10], 1);
                atomicAdd(&h[(relN + d4.z) >> 10], 1);
                atomicAdd(&h[(relN + d4.w) >> 10], 1);
            } else {
                for (int q = 0; q < 4; ++q) {
                    int ee = e + q;
                    if (ee < E) atomicAdd(&h[(relN + eg[E + ee]) >> 10], 1);
                }
            }
        }
        __syncthreads();
        for (int i = tid; i < nbuk; i += 256) counts[(size_t)bid * nbuk + i] = h[i];
    } else if (bid < NBLK + nbC) {
        // ---- x_image/x_text f32 -> bf16 ----
        int t = (bid - NBLK) * 256 + tid;
        int n8 = N * 16;
        if (t >= 2 * n8) return;
        int relc = (t >= n8) ? 1 : 0;
        const float* src = relc ? x_text : x_image;
        ushort* dst = relc ? xtb : xib;
        int i = relc ? t - n8 : t;
        float4 f0 = *reinterpret_cast<const float4*>(src + (size_t)i * 8);
        float4 f1 = *reinterpret_cast<const float4*>(src + (size_t)i * 8 + 4);
        u16x8 o;
        o[0] = f2b(f0.x); o[1] = f2b(f0.y); o[2] = f2b(f0.z); o[3] = f2b(f0.w);
        o[4] = f2b(f1.x); o[5] = f2b(f1.y); o[6] = f2b(f1.z); o[7] = f2b(f1.w);
        *reinterpret_cast<u16x8*>(dst + (size_t)i * 8) = o;
    } else {
        // ---- pack Bp [512x128] = [Wl_i; Wl_t; W_user@(Wr_i+Wr_t)] + bias ----
        int i = (bid - NBLK - nbC) * 256 + tid;      // < 65536
        int j = i & 7, lane = (i >> 3) & 63, cf = (i >> 9) & 7, ks = i >> 12;
        int kk = ks * 32 + (lane >> 4) * 8 + j;
        int col = cf * 16 + (lane & 15);
        float v;
        if (kk < 128)      v = Wl_i[kk * 128 + col];
        else if (kk < 256) v = Wl_t[(kk - 128) * 128 + col];
        else {
            int k2 = kk - 256;
            float s = 0.f;
            for (int c1 = 0; c1 < 128; ++c1)
                s += W_user[k2 * 128 + c1] * (Wr_i[c1 * 128 + col] + Wr_t[c1 * 128 + col]);
            v = s;
        }
        Bp[i] = f2b(v);
        if (i < 128) {
            float b = bl_i[i] + bl_t[i];
            for (int k2 = 0; k2 < 128; ++k2)
                b += b_user[k2] * (Wr_i[k2 * 128 + i] + Wr_t[k2 * 128 + i]);
            bias[i] = b;
        }
    }
}

// ---- s1: per-bucket exclusive prefix over blocks (in-place) + totals ----
__global__ __launch_bounds__(256) void k_s1(int* __restrict__ counts,
                                            int* __restrict__ T,
                                            int NBLK, int nbuk) {
    __shared__ int a[512];
    __shared__ int ps[256];
    const int b = blockIdx.x, t = threadIdx.x;
    a[t]       = (t < NBLK)       ? counts[(size_t)t * nbuk + b] : 0;
    a[t + 256] = (t + 256 < NBLK) ? counts[(size_t)(t + 256) * nbuk + b] : 0;
    __syncthreads();
    int x0 = a[2 * t], x1 = a[2 * t + 1];
    int s = x0 + x1;
    ps[t] = s; __syncthreads();
    for (int off = 1; off < 256; off <<= 1) {
        int add = (t >= off) ? ps[t - off] : 0;
        __syncthreads();
        ps[t] += add;
        __syncthreads();
    }
    int ex = ps[t] - s;
    if (2 * t < NBLK)     counts[(size_t)(2 * t) * nbuk + b] = ex;
    if (2 * t + 1 < NBLK) counts[(size_t)(2 * t + 1) * nbuk + b] = ex + x0;
    if (t == 255) T[b] = ps[255];
}

// ---- s2: exclusive scan of bucket totals -> bucket bases ----
__global__ __launch_bounds__(256) void k_s2(const int* __restrict__ T,
                                            int* __restrict__ Bb,
                                            int* __restrict__ rowptr,
                                            int M, int Etot, int nbuk) {
    __shared__ int sh[256];
    int t = threadIdx.x;
    int v = (t < nbuk) ? T[t] : 0;
    sh[t] = v; __syncthreads();
    for (int off = 1; off < 256; off <<= 1) {
        int add = (t >= off) ? sh[t - off] : 0;
        __syncthreads();
        sh[t] += add;
        __syncthreads();
    }
    if (t < nbuk) Bb[t] = sh[t] - v;
    if (t == 0) { Bb[nbuk] = Etot; rowptr[M] = Etot; }
}

// ---- part1: scatter (key,src) pairs into bucket regions via LDS cursors ----
__global__ __launch_bounds__(256) void k_part1(
        const int* __restrict__ edge_i, const int* __restrict__ edge_t,
        const int* __restrict__ counts, const int* __restrict__ Bb,
        int2* __restrict__ pairs, int N, int E, int nblkR, int nbuk) {
    __shared__ int cur[MAXBUK];
    const int bid = blockIdx.x, tid = threadIdx.x;
    int rel = (bid >= nblkR) ? 1 : 0;
    int blk = bid - rel * nblkR;
    const int* eg = rel ? edge_t : edge_i;
    const int relN = rel * N;
    for (int i = tid; i < nbuk; i += 256)
        cur[i] = Bb[i] + counts[(size_t)bid * nbuk + i];
    __syncthreads();
    int base = blk * BK;
    #pragma unroll
    for (int j = 0; j < 4; ++j) {
        int e = base + (j * 256 + tid) * 4;
        if (e + 3 < E) {
            int4 d4 = *reinterpret_cast<const int4*>(eg + E + e);
            int4 s4 = *reinterpret_cast<const int4*>(eg + e);
            int k0 = relN + d4.x, k1 = relN + d4.y, k2 = relN + d4.z, k3 = relN + d4.w;
            int p0 = atomicAdd(&cur[k0 >> 10], 1); pairs[p0] = make_int2(k0, s4.x);
            int p1 = atomicAdd(&cur[k1 >> 10], 1); pairs[p1] = make_int2(k1, s4.y);
            int p2 = atomicAdd(&cur[k2 >> 10], 1); pairs[p2] = make_int2(k2, s4.z);
            int p3 = atomicAdd(&cur[k3 >> 10], 1); pairs[p3] = make_int2(k3, s4.w);
        } else {
            for (int q = 0; q < 4; ++q) {
                int ee = e + q;
                if (ee < E) {
                    int k0 = relN + eg[E + ee];
                    int p0 = atomicAdd(&cur[k0 >> 10], 1);
                    pairs[p0] = make_int2(k0, eg[ee]);
                }
            }
        }
    }
}

// ---- part2: per-bucket (1024 keys) hist/scan -> rowptr + col ----
__global__ __launch_bounds__(256) void k_part2(
        const int2* __restrict__ pairs, const int* __restrict__ Bb,
        int* __restrict__ rowptr, int* __restrict__ col, int M) {
    __shared__ int h[1024];
    __shared__ int ps[256];
    const int b = blockIdx.x, t = threadIdx.x;
    const int key0 = b << 10;
    const int beg = Bb[b], end = Bb[b + 1];
    for (int i = t; i < 1024; i += 256) h[i] = 0;
    __syncthreads();
    for (int p = beg + t; p < end; p += 256)
        atomicAdd(&h[pairs[p].x - key0], 1);
    __syncthreads();
    int v0 = h[4 * t], v1 = h[4 * t + 1], v2 = h[4 * t + 2], v3 = h[4 * t + 3];
    int s = v0 + v1 + v2 + v3;
    ps[t] = s; __syncthreads();
    for (int off = 1; off < 256; off <<= 1) {
        int add = (t >= off) ? ps[t - off] : 0;
        __syncthreads();
        ps[t] += add;
        __syncthreads();
    }
    int run = ps[t] - s + beg;
    __syncthreads();
    int k = key0 + 4 * t;
    if (k + 0 < M) rowptr[k + 0] = run; h[4 * t + 0] = run; run += v0;
    if (k + 1 < M) rowptr[k + 1] = run; h[4 * t + 1] = run; run += v1;
    if (k + 2 < M) rowptr[k + 2] = run; h[4 * t + 2] = run; run += v2;
    if (k + 3 < M) rowptr[k + 3] = run; h[4 * t + 3] = run;
    __syncthreads();
    for (int p = beg + t; p < end; p += 256) {
        int2 pr = pairs[p];
        int slot = atomicAdd(&h[pr.x - key0], 1);
        col[slot] = pr.y;
    }
}

// ---- gather-mean: 8 lanes/node, 32B/lane, unroll-4, bf16 in/out ----
__global__ __launch_bounds__(256) void k_gather_mean(
        const ushort* __restrict__ xib, const ushort* __restrict__ xtb,
        const int* __restrict__ rowptr, const int* __restrict__ col,
        ushort* __restrict__ mi, ushort* __restrict__ mt, int N) {
    int t = blockIdx.x * 256 + threadIdx.x;
    int node = t >> 3, lane = t & 7;
    if (node >= N) return;
    int rel = blockIdx.y;
    const ushort* xs = rel ? xtb : xib;
    ushort* mean = rel ? mt : mi;
    const int c0 = lane * 16;
    int rb = rel * N + node;
    int beg = rowptr[rb], end = rowptr[rb + 1];
    float a[16];
    #pragma unroll
    for (int q = 0; q < 16; ++q) a[q] = 0.f;
    int j = beg;
    for (; j + 3 < end; j += 4) {
        int s0 = col[j], s1 = col[j + 1], s2 = col[j + 2], s3 = col[j + 3];
        const ushort* r0 = xs + (size_t)s0 * 128 + c0;
        const ushort* r1 = xs + (size_t)s1 * 128 + c0;
        const ushort* r2 = xs + (size_t)s2 * 128 + c0;
        const ushort* r3 = xs + (size_t)s3 * 128 + c0;
        u16x8 v0a = *reinterpret_cast<const u16x8*>(r0);
        u16x8 v0b = *reinterpret_cast<const u16x8*>(r0 + 8);
        u16x8 v1a = *reinterpret_cast<const u16x8*>(r1);
        u16x8 v1b = *reinterpret_cast<const u16x8*>(r1 + 8);
        u16x8 v2a = *reinterpret_cast<const u16x8*>(r2);
        u16x8 v2b = *reinterpret_cast<const u16x8*>(r2 + 8);
        u16x8 v3a = *reinterpret_cast<const u16x8*>(r3);
        u16x8 v3b = *reinterpret_cast<const u16x8*>(r3 + 8);
        #pragma unroll
        for (int q = 0; q < 8; ++q) {
            a[q]     += (b2f(v0a[q]) + b2f(v1a[q])) + (b2f(v2a[q]) + b2f(v3a[q]));
            a[q + 8] += (b2f(v0b[q]) + b2f(v1b[q])) + (b2f(v2b[q]) + b2f(v3b[q]));
        }
    }
    for (; j < end; ++j) {
        const ushort* r0 = xs + (size_t)col[j] * 128 + c0;
        u16x8 v0a = *reinterpret_cast<const u16x8*>(r0);
        u16x8 v0b = *reinterpret_cast<const u16x8*>(r0 + 8);
        #pragma unroll
        for (int q = 0; q < 8; ++q) { a[q] += b2f(v0a[q]); a[q + 8] += b2f(v0b[q]); }
    }
    float r = (end > beg) ? 1.0f / (float)(end - beg) : 0.0f;
    u16x8 o0, o1;
    #pragma unroll
    for (int q = 0; q < 8; ++q) { o0[q] = f2b(a[q] * r); o1[q] = f2b(a[q + 8] * r); }
    *reinterpret_cast<u16x8*>(mean + (size_t)node * 128 + c0) = o0;
    *reinterpret_cast<u16x8*>(mean + (size_t)node * 128 + c0 + 8) = o1;
}

// ---- out = relu( [mi|mt|x_user](K=512) @ Bp + bias ) : MFMA, B in LDS ----
// 512 thr / 8 waves, 256 rows per block (32 rows/wave), B staged in 2x64KB.
__global__ __launch_bounds__(512) void k_final_mfma(
        const ushort* __restrict__ mi, const ushort* __restrict__ mt,
        const float* __restrict__ x_user, const ushort* __restrict__ Bp,
        const float* __restrict__ bias, float* __restrict__ out, int N) {
    __shared__ u16x8 bl8[4096];                  // 64 KB half of B
    const int tid = threadIdx.x;
    const int wid = tid >> 6, lane = tid & 63;
    const int r0g = blockIdx.x * 256 + wid * 32 + (lane & 15);
    const int rA0 = min(r0g, N - 1);
    const int rA1 = min(r0g + 16, N - 1);
    const int kh = (lane >> 4) * 8;
    f32x4 acc0[8] = {}, acc1[8] = {};

    const u16x8* Bp8 = reinterpret_cast<const u16x8*>(Bp);

    #pragma unroll
    for (int h = 0; h < 2; ++h) {
        // ---- stage 64KB half of B into LDS (linear copy) ----
        if (h) __syncthreads();                  // protect previous half's reads
        #pragma unroll
        for (int it = 0; it < 8; ++it)
            bl8[it * 512 + tid] = Bp8[h * 4096 + it * 512 + tid];
        __syncthreads();

        if (h == 0) {
            // ---- ks 0..7: A from mi/mt (bf16) ----
            #pragma unroll
            for (int ks = 0; ks < 8; ++ks) {
                const ushort* s = (ks < 4) ? mi : mt;
                bf16x8 a0 = *reinterpret_cast<const bf16x8*>(s + (size_t)rA0 * 128 + (ks & 3) * 32 + kh);
                bf16x8 a1 = *reinterpret_cast<const bf16x8*>(s + (size_t)rA1 * 128 + (ks & 3) * 32 + kh);
                #pragma unroll
                for (int cf = 0; cf < 8; ++cf) {
                    bf16x8 bb = *reinterpret_cast<const bf16x8*>(&bl8[(ks * 8 + cf) * 64 + lane]);
                    acc0[cf] = __builtin_amdgcn_mfma_f32_16x16x32_bf16(a0, bb, acc0[cf], 0, 0, 0);
                    acc1[cf] = __builtin_amdgcn_mfma_f32_16x16x32_bf16(a1, bb, acc1[cf], 0, 0, 0);
                }
            }
        } else {
            // ---- ks 8..15: A from x_user (f32, inline cvt) ----
            const float* Xr0 = x_user + (size_t)rA0 * 256;
            const float* Xr1 = x_user + (size_t)rA1 * 256;
            #pragma unroll
            for (int ks = 0; ks < 8; ++ks) {
                int k0 = ks * 32 + kh;
                float4 f0 = *reinterpret_cast<const float4*>(Xr0 + k0);
                float4 f1 = *reinterpret_cast<const float4*>(Xr0 + k0 + 4);
                float4 g0 = *reinterpret_cast<const float4*>(Xr1 + k0);
                float4 g1 = *reinterpret_cast<const float4*>(Xr1 + k0 + 4);
                bf16x8 a0, a1;
                a0[0] = (short)f2b(f0.x); a0[1] = (short)f2b(f0.y);
                a0[2] = (short)f2b(f0.z); a0[3] = (short)f2b(f0.w);
                a0[4] = (short)f2b(f1.x); a0[5] = (short)f2b(f1.y);
                a0[6] = (short)f2b(f1.z); a0[7] = (short)f2b(f1.w);
                a1[0] = (short)f2b(g0.x); a1[1] = (short)f2b(g0.y);
                a1[2] = (short)f2b(g0.z); a1[3] = (short)f2b(g0.w);
                a1[4] = (short)f2b(g1.x); a1[5] = (short)f2b(g1.y);
                a1[6] = (short)f2b(g1.z); a1[7] = (short)f2b(g1.w);
                #pragma unroll
                for (int cf = 0; cf < 8; ++cf) {
                    bf16x8 bb = *reinterpret_cast<const bf16x8*>(&bl8[(ks * 8 + cf) * 64 + lane]);
                    acc0[cf] = __builtin_amdgcn_mfma_f32_16x16x32_bf16(a0, bb, acc0[cf], 0, 0, 0);
                    acc1[cf] = __builtin_amdgcn_mfma_f32_16x16x32_bf16(a1, bb, acc1[cf], 0, 0, 0);
                }
            }
        }
    }

    // ---- epilogue: bias + relu + store (2 row groups) ----
    const int col0 = lane & 15;
    const int rbase = blockIdx.x * 256 + wid * 32 + (lane >> 4) * 4;
    #pragma unroll
    for (int cf = 0; cf < 8; ++cf) {
        int c = cf * 16 + col0;
        float bv = bias[c];
        #pragma unroll
        for (int r = 0; r < 4; ++r) {
            int row = rbase + r;
            if (row < N) out[(size_t)row * 128 + c] = fmaxf(acc0[cf][r] + bv, 0.f);
            int row2 = rbase + 16 + r;
            if (row2 < N) out[(size_t)row2 * 128 + c] = fmaxf(acc1[cf][r] + bv, 0.f);
        }
    }
}

extern "C" void kernel_launch(void* const* d_in, const int* in_sizes, int n_in,
                              void* d_out, int out_size, void* d_ws, size_t ws_size,
                              hipStream_t stream) {
    const float* x_user  = (const float*)d_in[0];
    const float* x_image = (const float*)d_in[1];
    const float* x_text  = (const float*)d_in[2];
    const int*   edge_i  = (const int*)d_in[3];
    const int*   edge_t  = (const int*)d_in[4];
    const float* W_user  = (const float*)d_in[5];
    const float* b_user  = (const float*)d_in[6];
    const float* Wl_img  = (const float*)d_in[7];
    const float* bl_img  = (const float*)d_in[8];
    const float* Wr_img  = (const float*)d_in[9];
    const float* Wl_txt  = (const float*)d_in[10];
    const float* bl_txt  = (const float*)d_in[11];
    const float* Wr_txt  = (const float*)d_in[12];

    const int N = in_sizes[0] / 256;   // 100000 nodes per type
    const int E = in_sizes[3] / 2;     // 800000 edges per relation
    const int M = 2 * N;
    const int nblkR = (E + BK - 1) / BK;           // 196
    const int NBLK = 2 * nblkR;                    // 392 (<=512 for k_s1)
    const int nbuk = (M + 1023) >> 10;             // 196 (<=MAXBUK)

    ushort* xib    = (ushort*)d_ws;                // N*128
    ushort* xtb    = xib + (size_t)N * 128;        // N*128
    ushort* mi     = xtb + (size_t)N * 128;        // N*128
    ushort* mt     = mi  + (size_t)N * 128;        // N*128
    ushort* Bp     = mt  + (size_t)N * 128;        // 65536
    float*  bias   = (float*)(Bp + 65536);         // 128
    int*    counts = (int*)(bias + 128);           // NBLK*nbuk
    int*    T      = counts + (size_t)NBLK * nbuk; // 256
    int*    Bb     = T + 256;                      // nbuk+1 (pad 260)
    int*    rowptr = Bb + 260;                     // M+4
    int*    col    = rowptr + (M + 4);             // 2E
    int2*   pairs  = (int2*)(col + (size_t)2 * E); // 2E int2

    const int nbC = (2 * N * 16 + 255) / 256;      // convert blocks (img+txt)
    const int nbP = 256;                           // pack blocks (65536 thr)
    k_front<<<NBLK + nbC + nbP, 256, 0, stream>>>(
        x_image, x_text, edge_i, edge_t,
        Wl_img, Wl_txt, W_user, b_user, Wr_img, Wr_txt, bl_img, bl_txt,
        xib, xtb, Bp, bias, counts, N, E, nblkR, nbuk, nbC);

    k_s1<<<nbuk, 256, 0, stream>>>(counts, T, NBLK, nbuk);
    k_s2<<<1, 256, 0, stream>>>(T, Bb, rowptr, M, 2 * E, nbuk);
    k_part1<<<NBLK, 256, 0, stream>>>(edge_i, edge_t, counts, Bb, pairs,
                                      N, E, nblkR, nbuk);
    k_part2<<<nbuk, 256, 0, stream>>>(pairs, Bb, rowptr, col, M);

    {
        dim3 g((N * 8 + 255) / 256, 2);
        k_gather_mean<<<g, 256, 0, stream>>>(xib, xtb, rowptr, col, mi, mt, N);
    }

    k_final_mfma<<<(N + 255) / 256, 512, 0, stream>>>(
        mi, mt, x_user, Bp, bias, (float*)d_out, N);
}

// Round 14
// 179.067 us; speedup vs baseline: 1.2697x; 1.1158x over previous
//
#include <hip/hip_runtime.h>

// ---------------------------------------------------------------------------
// HeteroGNN, round 14: front block-range reorder (pack|hist|convert) +
// u32-packed pairs + 512-thread partition kernels.
//   out = relu( [mean_i | mean_t | x_user] @ [Wl_i; Wl_t; W_user@(Wr_i+Wr_t)]
//               + (b_user@(Wr_i+Wr_t) + bl_i + bl_t) )        [MFMA, K=512]
// CSR: two-level bucket partition, zero global atomics.
//   pair = (key&1023)<<17 | src   (src < 2^17)
// gather: 8 lanes/node, 32B/lane, unroll-4, bf16 (r11/r13 — measured best).
// final: 512thr/256rows, 2x64KB LDS B-halves, x_user f32 inline cvt (r10).
// MFMA 16x16x32_bf16: A row=lane&15, k=(lane>>4)*8+j; B col=lane&15;
// D col=lane&15, row=(lane>>4)*4+reg  [m89-verified].
// ---------------------------------------------------------------------------

#define BK 4096          // edges per level-1 block
#define MAXBUK 256       // >= nbuk = ceil(2N/1024) = 196

typedef __attribute__((ext_vector_type(8))) short bf16x8;
typedef __attribute__((ext_vector_type(8))) unsigned short u16x8;
typedef __attribute__((ext_vector_type(4))) float f32x4;

__device__ __forceinline__ ushort f2b(float x) {
    union { float f; unsigned u; } v; v.f = x;
    unsigned r = (v.u + 0x7FFF + ((v.u >> 16) & 1)) >> 16;   // RNE
    return (ushort)r;
}
__device__ __forceinline__ float b2f(ushort u) {
    union { unsigned u; float f; } v; v.u = (unsigned)u << 16;
    return v.f;
}

// ---- fused front: [pack | bucket hist (LDS) | bf16 convert] by block range ----
__global__ __launch_bounds__(256) void k_front(
        const float* __restrict__ x_image, const float* __restrict__ x_text,
        const int* __restrict__ edge_i, const int* __restrict__ edge_t,
        const float* __restrict__ Wl_i, const float* __restrict__ Wl_t,
        const float* __restrict__ W_user, const float* __restrict__ b_user,
        const float* __restrict__ Wr_i, const float* __restrict__ Wr_t,
        const float* __restrict__ bl_i, const float* __restrict__ bl_t,
        ushort* __restrict__ xib, ushort* __restrict__ xtb,
        ushort* __restrict__ Bp, float* __restrict__ bias,
        int* __restrict__ counts,
        int N, int E, int nblkR, int nbuk, int nbP) {
    __shared__ int h[MAXBUK];
    const int bid = blockIdx.x;
    const int tid = threadIdx.x;
    const int NBLK = 2 * nblkR;

    if (bid < nbP) {
        // ---- pack Bp [512x128] = [Wl_i; Wl_t; W_user@(Wr_i+Wr_t)] + bias ----
        int i = bid * 256 + tid;                     // < 65536
        int j = i & 7, lane = (i >> 3) & 63, cf = (i >> 9) & 7, ks = i >> 12;
        int kk = ks * 32 + (lane >> 4) * 8 + j;
        int col = cf * 16 + (lane & 15);
        float v;
        if (kk < 128)      v = Wl_i[kk * 128 + col];
        else if (kk < 256) v = Wl_t[(kk - 128) * 128 + col];
        else {
            int k2 = kk - 256;
            float s = 0.f;
            for (int c1 = 0; c1 < 128; ++c1)
                s += W_user[k2 * 128 + c1] * (Wr_i[c1 * 128 + col] + Wr_t[c1 * 128 + col]);
            v = s;
        }
        Bp[i] = f2b(v);
        if (i < 128) {
            float b = bl_i[i] + bl_t[i];
            for (int k2 = 0; k2 < 128; ++k2)
                b += b_user[k2] * (Wr_i[k2 * 128 + i] + Wr_t[k2 * 128 + i]);
            bias[i] = b;
        }
    } else if (bid < nbP + NBLK) {
        // ---- level-1 histogram of bucket = key>>10, LDS atomics only ----
        int hb = bid - nbP;
        int rel = (hb >= nblkR) ? 1 : 0;
        int blk = hb - rel * nblkR;
        const int* eg = rel ? edge_t : edge_i;
        const int relN = rel * N;
        for (int i = tid; i < nbuk; i += 256) h[i] = 0;
        __syncthreads();
        int base = blk * BK;
        #pragma unroll
        for (int j = 0; j < 4; ++j) {
            int e = base + (j * 256 + tid) * 4;
            if (e + 3 < E) {
                int4 d4 = *reinterpret_cast<const int4*>(eg + E + e);
                atomicAdd(&h[(relN + d4.x) >> 10], 1);
                atomicAdd(&h[(relN + d4.y) >> 10], 1);
                atomicAdd(&h[(relN + d4.z) >> 10], 1);
                atomicAdd(&h[(relN + d4.w) >> 10], 1);
            } else {
                for (int q = 0; q < 4; ++q) {
                    int ee = e + q;
                    if (ee < E) atomicAdd(&h[(relN + eg[E + ee]) >> 10], 1);
                }
            }
        }
        __syncthreads();
        for (int i = tid; i < nbuk; i += 256) counts[(size_t)hb * nbuk + i] = h[i];
    } else {
        // ---- x_image/x_text f32 -> bf16 ----
        int t = (bid - nbP - NBLK) * 256 + tid;
        int n8 = N * 16;
        if (t >= 2 * n8) return;
        int relc = (t >= n8) ? 1 : 0;
        const float* src = relc ? x_text : x_image;
        ushort* dst = relc ? xtb : xib;
        int i = relc ? t - n8 : t;
        float4 f0 = *reinterpret_cast<const float4*>(src + (size_t)i * 8);
        float4 f1 = *reinterpret_cast<const float4*>(src + (size_t)i * 8 + 4);
        u16x8 o;
        o[0] = f2b(f0.x); o[1] = f2b(f0.y); o[2] = f2b(f0.z); o[3] = f2b(f0.w);
        o[4] = f2b(f1.x); o[5] = f2b(f1.y); o[6] = f2b(f1.z); o[7] = f2b(f1.w);
        *reinterpret_cast<u16x8*>(dst + (size_t)i * 8) = o;
    }
}

// ---- s1: per-bucket exclusive prefix over blocks (in-place) + totals ----
__global__ __launch_bounds__(256) void k_s1(int* __restrict__ counts,
                                            int* __restrict__ T,
                                            int NBLK, int nbuk) {
    __shared__ int a[512];
    __shared__ int ps[256];
    const int b = blockIdx.x, t = threadIdx.x;
    a[t]       = (t < NBLK)       ? counts[(size_t)t * nbuk + b] : 0;
    a[t + 256] = (t + 256 < NBLK) ? counts[(size_t)(t + 256) * nbuk + b] : 0;
    __syncthreads();
    int x0 = a[2 * t], x1 = a[2 * t + 1];
    int s = x0 + x1;
    ps[t] = s; __syncthreads();
    for (int off = 1; off < 256; off <<= 1) {
        int add = (t >= off) ? ps[t - off] : 0;
        __syncthreads();
        ps[t] += add;
        __syncthreads();
    }
    int ex = ps[t] - s;
    if (2 * t < NBLK)     counts[(size_t)(2 * t) * nbuk + b] = ex;
    if (2 * t + 1 < NBLK) counts[(size_t)(2 * t + 1) * nbuk + b] = ex + x0;
    if (t == 255) T[b] = ps[255];
}

// ---- s2: exclusive scan of bucket totals -> bucket bases ----
__global__ __launch_bounds__(256) void k_s2(const int* __restrict__ T,
                                            int* __restrict__ Bb,
                                            int* __restrict__ rowptr,
                                            int M, int Etot, int nbuk) {
    __shared__ int sh[256];
    int t = threadIdx.x;
    int v = (t < nbuk) ? T[t] : 0;
    sh[t] = v; __syncthreads();
    for (int off = 1; off < 256; off <<= 1) {
        int add = (t >= off) ? sh[t - off] : 0;
        __syncthreads();
        sh[t] += add;
        __syncthreads();
    }
    if (t < nbuk) Bb[t] = sh[t] - v;
    if (t == 0) { Bb[nbuk] = Etot; rowptr[M] = Etot; }
}

// ---- part1 (512 thr): scatter packed pairs into bucket regions ----
__global__ __launch_bounds__(512) void k_part1(
        const int* __restrict__ edge_i, const int* __restrict__ edge_t,
        const int* __restrict__ counts, const int* __restrict__ Bb,
        unsigned* __restrict__ pairs, int N, int E, int nblkR, int nbuk) {
    __shared__ int cur[MAXBUK];
    const int bid = blockIdx.x, tid = threadIdx.x;
    int rel = (bid >= nblkR) ? 1 : 0;
    int blk = bid - rel * nblkR;
    const int* eg = rel ? edge_t : edge_i;
    const int relN = rel * N;
    for (int i = tid; i < nbuk; i += 512)
        cur[i] = Bb[i] + counts[(size_t)bid * nbuk + i];
    __syncthreads();
    int base = blk * BK;
    #pragma unroll
    for (int j = 0; j < 2; ++j) {
        int e = base + (j * 512 + tid) * 4;
        if (e + 3 < E) {
            int4 d4 = *reinterpret_cast<const int4*>(eg + E + e);
            int4 s4 = *reinterpret_cast<const int4*>(eg + e);
            int k0 = relN + d4.x, k1 = relN + d4.y, k2 = relN + d4.z, k3 = relN + d4.w;
            int p0 = atomicAdd(&cur[k0 >> 10], 1);
            pairs[p0] = ((unsigned)(k0 & 1023) << 17) | (unsigned)s4.x;
            int p1 = atomicAdd(&cur[k1 >> 10], 1);
            pairs[p1] = ((unsigned)(k1 & 1023) << 17) | (unsigned)s4.y;
            int p2 = atomicAdd(&cur[k2 >> 10], 1);
            pairs[p2] = ((unsigned)(k2 & 1023) << 17) | (unsigned)s4.z;
            int p3 = atomicAdd(&cur[k3 >> 10], 1);
            pairs[p3] = ((unsigned)(k3 & 1023) << 17) | (unsigned)s4.w;
        } else {
            for (int q = 0; q < 4; ++q) {
                int ee = e + q;
                if (ee < E) {
                    int k0 = relN + eg[E + ee];
                    int p0 = atomicAdd(&cur[k0 >> 10], 1);
                    pairs[p0] = ((unsigned)(k0 & 1023) << 17) | (unsigned)eg[ee];
                }
            }
        }
    }
}

// ---- part2 (512 thr): per-bucket (1024 keys) hist/scan -> rowptr + col ----
__global__ __launch_bounds__(512) void k_part2(
        const unsigned* __restrict__ pairs, const int* __restrict__ Bb,
        int* __restrict__ rowptr, int* __restrict__ col, int M) {
    __shared__ int h[1024];
    __shared__ int ps[512];
    const int b = blockIdx.x, t = threadIdx.x;
    const int key0 = b << 10;
    const int beg = Bb[b], end = Bb[b + 1];
    h[t] = 0; h[t + 512] = 0;
    __syncthreads();
    for (int p = beg + t; p < end; p += 512)
        atomicAdd(&h[pairs[p] >> 17], 1);
    __syncthreads();
    int v0 = h[2 * t], v1 = h[2 * t + 1];
    int s = v0 + v1;
    ps[t] = s; __syncthreads();
    for (int off = 1; off < 512; off <<= 1) {
        int add = (t >= off) ? ps[t - off] : 0;
        __syncthreads();
        ps[t] += add;
        __syncthreads();
    }
    int run = ps[t] - s + beg;
    __syncthreads();
    int k = key0 + 2 * t;
    if (k < M) rowptr[k] = run;
    h[2 * t] = run; run += v0;
    if (k + 1 < M) rowptr[k + 1] = run;
    h[2 * t + 1] = run;
    __syncthreads();
    for (int p = beg + t; p < end; p += 512) {
        unsigned pr = pairs[p];
        int slot = atomicAdd(&h[pr >> 17], 1);
        col[slot] = (int)(pr & 0x1FFFFu);
    }
}

// ---- gather-mean: 8 lanes/node, 32B/lane, unroll-4, bf16 in/out ----
__global__ __launch_bounds__(256) void k_gather_mean(
        const ushort* __restrict__ xib, const ushort* __restrict__ xtb,
        const int* __restrict__ rowptr, const int* __restrict__ col,
        ushort* __restrict__ mi, ushort* __restrict__ mt, int N) {
    int t = blockIdx.x * 256 + threadIdx.x;
    int node = t >> 3, lane = t & 7;
    if (node >= N) return;
    int rel = blockIdx.y;
    const ushort* xs = rel ? xtb : xib;
    ushort* mean = rel ? mt : mi;
    const int c0 = lane * 16;
    int rb = rel * N + node;
    int beg = rowptr[rb], end = rowptr[rb + 1];
    float a[16];
    #pragma unroll
    for (int q = 0; q < 16; ++q) a[q] = 0.f;
    int j = beg;
    for (; j + 3 < end; j += 4) {
        int s0 = col[j], s1 = col[j + 1], s2 = col[j + 2], s3 = col[j + 3];
        const ushort* r0 = xs + (size_t)s0 * 128 + c0;
        const ushort* r1 = xs + (size_t)s1 * 128 + c0;
        const ushort* r2 = xs + (size_t)s2 * 128 + c0;
        const ushort* r3 = xs + (size_t)s3 * 128 + c0;
        u16x8 v0a = *reinterpret_cast<const u16x8*>(r0);
        u16x8 v0b = *reinterpret_cast<const u16x8*>(r0 + 8);
        u16x8 v1a = *reinterpret_cast<const u16x8*>(r1);
        u16x8 v1b = *reinterpret_cast<const u16x8*>(r1 + 8);
        u16x8 v2a = *reinterpret_cast<const u16x8*>(r2);
        u16x8 v2b = *reinterpret_cast<const u16x8*>(r2 + 8);
        u16x8 v3a = *reinterpret_cast<const u16x8*>(r3);
        u16x8 v3b = *reinterpret_cast<const u16x8*>(r3 + 8);
        #pragma unroll
        for (int q = 0; q < 8; ++q) {
            a[q]     += (b2f(v0a[q]) + b2f(v1a[q])) + (b2f(v2a[q]) + b2f(v3a[q]));
            a[q + 8] += (b2f(v0b[q]) + b2f(v1b[q])) + (b2f(v2b[q]) + b2f(v3b[q]));
        }
    }
    for (; j < end; ++j) {
        const ushort* r0 = xs + (size_t)col[j] * 128 + c0;
        u16x8 v0a = *reinterpret_cast<const u16x8*>(r0);
        u16x8 v0b = *reinterpret_cast<const u16x8*>(r0 + 8);
        #pragma unroll
        for (int q = 0; q < 8; ++q) { a[q] += b2f(v0a[q]); a[q + 8] += b2f(v0b[q]); }
    }
    float r = (end > beg) ? 1.0f / (float)(end - beg) : 0.0f;
    u16x8 o0, o1;
    #pragma unroll
    for (int q = 0; q < 8; ++q) { o0[q] = f2b(a[q] * r); o1[q] = f2b(a[q + 8] * r); }
    *reinterpret_cast<u16x8*>(mean + (size_t)node * 128 + c0) = o0;
    *reinterpret_cast<u16x8*>(mean + (size_t)node * 128 + c0 + 8) = o1;
}

// ---- out = relu( [mi|mt|x_user](K=512) @ Bp + bias ) : MFMA, B in LDS ----
// 512 thr / 8 waves, 256 rows per block (32 rows/wave), B staged in 2x64KB.
__global__ __launch_bounds__(512) void k_final_mfma(
        const ushort* __restrict__ mi, const ushort* __restrict__ mt,
        const float* __restrict__ x_user, const ushort* __restrict__ Bp,
        const float* __restrict__ bias, float* __restrict__ out, int N) {
    __shared__ u16x8 bl8[4096];                  // 64 KB half of B
    const int tid = threadIdx.x;
    const int wid = tid >> 6, lane = tid & 63;
    const int r0g = blockIdx.x * 256 + wid * 32 + (lane & 15);
    const int rA0 = min(r0g, N - 1);
    const int rA1 = min(r0g + 16, N - 1);
    const int kh = (lane >> 4) * 8;
    f32x4 acc0[8] = {}, acc1[8] = {};

    const u16x8* Bp8 = reinterpret_cast<const u16x8*>(Bp);

    #pragma unroll
    for (int h = 0; h < 2; ++h) {
        // ---- stage 64KB half of B into LDS (linear copy) ----
        if (h) __syncthreads();                  // protect previous half's reads
        #pragma unroll
        for (int it = 0; it < 8; ++it)
            bl8[it * 512 + tid] = Bp8[h * 4096 + it * 512 + tid];
        __syncthreads();

        if (h == 0) {
            // ---- ks 0..7: A from mi/mt (bf16) ----
            #pragma unroll
            for (int ks = 0; ks < 8; ++ks) {
                const ushort* s = (ks < 4) ? mi : mt;
                bf16x8 a0 = *reinterpret_cast<const bf16x8*>(s + (size_t)rA0 * 128 + (ks & 3) * 32 + kh);
                bf16x8 a1 = *reinterpret_cast<const bf16x8*>(s + (size_t)rA1 * 128 + (ks & 3) * 32 + kh);
                #pragma unroll
                for (int cf = 0; cf < 8; ++cf) {
                    bf16x8 bb = *reinterpret_cast<const bf16x8*>(&bl8[(ks * 8 + cf) * 64 + lane]);
                    acc0[cf] = __builtin_amdgcn_mfma_f32_16x16x32_bf16(a0, bb, acc0[cf], 0, 0, 0);
                    acc1[cf] = __builtin_amdgcn_mfma_f32_16x16x32_bf16(a1, bb, acc1[cf], 0, 0, 0);
                }
            }
        } else {
            // ---- ks 8..15: A from x_user (f32, inline cvt) ----
            const float* Xr0 = x_user + (size_t)rA0 * 256;
            const float* Xr1 = x_user + (size_t)rA1 * 256;
            #pragma unroll
            for (int ks = 0; ks < 8; ++ks) {
                int k0 = ks * 32 + kh;
                float4 f0 = *reinterpret_cast<const float4*>(Xr0 + k0);
                float4 f1 = *reinterpret_cast<const float4*>(Xr0 + k0 + 4);
                float4 g0 = *reinterpret_cast<const float4*>(Xr1 + k0);
                float4 g1 = *reinterpret_cast<const float4*>(Xr1 + k0 + 4);
                bf16x8 a0, a1;
                a0[0] = (short)f2b(f0.x); a0[1] = (short)f2b(f0.y);
                a0[2] = (short)f2b(f0.z); a0[3] = (short)f2b(f0.w);
                a0[4] = (short)f2b(f1.x); a0[5] = (short)f2b(f1.y);
                a0[6] = (short)f2b(f1.z); a0[7] = (short)f2b(f1.w);
                a1[0] = (short)f2b(g0.x); a1[1] = (short)f2b(g0.y);
                a1[2] = (short)f2b(g0.z); a1[3] = (short)f2b(g0.w);
                a1[4] = (short)f2b(g1.x); a1[5] = (short)f2b(g1.y);
                a1[6] = (short)f2b(g1.z); a1[7] = (short)f2b(g1.w);
                #pragma unroll
                for (int cf = 0; cf < 8; ++cf) {
                    bf16x8 bb = *reinterpret_cast<const bf16x8*>(&bl8[(ks * 8 + cf) * 64 + lane]);
                    acc0[cf] = __builtin_amdgcn_mfma_f32_16x16x32_bf16(a0, bb, acc0[cf], 0, 0, 0);
                    acc1[cf] = __builtin_amdgcn_mfma_f32_16x16x32_bf16(a1, bb, acc1[cf], 0, 0, 0);
                }
            }
        }
    }

    // ---- epilogue: bias + relu + store (2 row groups) ----
    const int col0 = lane & 15;
    const int rbase = blockIdx.x * 256 + wid * 32 + (lane >> 4) * 4;
    #pragma unroll
    for (int cf = 0; cf < 8; ++cf) {
        int c = cf * 16 + col0;
        float bv = bias[c];
        #pragma unroll
        for (int r = 0; r < 4; ++r) {
            int row = rbase + r;
            if (row < N) out[(size_t)row * 128 + c] = fmaxf(acc0[cf][r] + bv, 0.f);
            int row2 = rbase + 16 + r;
            if (row2 < N) out[(size_t)row2 * 128 + c] = fmaxf(acc1[cf][r] + bv, 0.f);
        }
    }
}

extern "C" void kernel_launch(void* const* d_in, const int* in_sizes, int n_in,
                              void* d_out, int out_size, void* d_ws, size_t ws_size,
                              hipStream_t stream) {
    const float* x_user  = (const float*)d_in[0];
    const float* x_image = (const float*)d_in[1];
    const float* x_text  = (const float*)d_in[2];
    const int*   edge_i  = (const int*)d_in[3];
    const int*   edge_t  = (const int*)d_in[4];
    const float* W_user  = (const float*)d_in[5];
    const float* b_user  = (const float*)d_in[6];
    const float* Wl_img  = (const float*)d_in[7];
    const float* bl_img  = (const float*)d_in[8];
    const float* Wr_img  = (const float*)d_in[9];
    const float* Wl_txt  = (const float*)d_in[10];
    const float* bl_txt  = (const float*)d_in[11];
    const float* Wr_txt  = (const float*)d_in[12];

    const int N = in_sizes[0] / 256;   // 100000 nodes per type
    const int E = in_sizes[3] / 2;     // 800000 edges per relation
    const int M = 2 * N;
    const int nblkR = (E + BK - 1) / BK;           // 196
    const int NBLK = 2 * nblkR;                    // 392 (<=512 for k_s1)
    const int nbuk = (M + 1023) >> 10;             // 196 (<=MAXBUK)

    ushort*   xib    = (ushort*)d_ws;                // N*128
    ushort*   xtb    = xib + (size_t)N * 128;        // N*128
    ushort*   mi     = xtb + (size_t)N * 128;        // N*128
    ushort*   mt     = mi  + (size_t)N * 128;        // N*128
    ushort*   Bp     = mt  + (size_t)N * 128;        // 65536
    float*    bias   = (float*)(Bp + 65536);         // 128
    int*      counts = (int*)(bias + 128);           // NBLK*nbuk
    int*      T      = counts + (size_t)NBLK * nbuk; // 256
    int*      Bb     = T + 256;                      // nbuk+1 (pad 260)
    int*      rowptr = Bb + 260;                     // M+4
    int*      col    = rowptr + (M + 4);             // 2E
    unsigned* pairs  = (unsigned*)(col + (size_t)2 * E); // 2E u32

    const int nbP = 256;                           // pack blocks (65536 thr)
    const int nbC = (2 * N * 16 + 255) / 256;      // convert blocks (img+txt)
    k_front<<<nbP + NBLK + nbC, 256, 0, stream>>>(
        x_image, x_text, edge_i, edge_t,
        Wl_img, Wl_txt, W_user, b_user, Wr_img, Wr_txt, bl_img, bl_txt,
        xib, xtb, Bp, bias, counts, N, E, nblkR, nbuk, nbP);

    k_s1<<<nbuk, 256, 0, stream>>>(counts, T, NBLK, nbuk);
    k_s2<<<1, 256, 0, stream>>>(T, Bb, rowptr, M, 2 * E, nbuk);
    k_part1<<<NBLK, 512, 0, stream>>>(edge_i, edge_t, counts, Bb, pairs,
                                      N, E, nblkR, nbuk);
    k_part2<<<nbuk, 512, 0, stream>>>(pairs, Bb, rowptr, col, M);

    {
        dim3 g((N * 8 + 255) / 256, 2);
        k_gather_mean<<<g, 256, 0, stream>>>(xib, xtb, rowptr, col, mi, mt, N);
    }

    k_final_mfma<<<(N + 255) / 256, 512, 0, stream>>>(
        mi, mt, x_user, Bp, bias, (float*)d_out, N);
}

// Round 15
// 154.567 us; speedup vs baseline: 1.4710x; 1.1585x over previous
//
#include <hip/hip_runtime.h>

// ---------------------------------------------------------------------------
// HeteroGNN, round 15: fp8-e4m3 gather tables (halve gather traffic).
//   x_image/x_text stored fp8 (HW cvt_pk encode/decode); means bf16; all
//   GEMMs bf16 MFMA with f32 accum (unchanged).
//   out = relu( [mean_i | mean_t | x_user] @ [Wl_i; Wl_t; W_user@(Wr_i+Wr_t)]
//               + (b_user@(Wr_i+Wr_t) + bl_i + bl_t) )        [MFMA, K=512]
// CSR: two-level bucket partition, zero global atomics (r9/r14).
// gather: 8 lanes/node, 16B(=16 elems)/lane, unroll-4.
// final: 512thr/256rows, 2x64KB LDS B-halves, x_user f32 inline cvt (r10).
// MFMA 16x16x32_bf16: A row=lane&15, k=(lane>>4)*8+j; B col=lane&15;
// D col=lane&15, row=(lane>>4)*4+reg  [m89-verified].
// ---------------------------------------------------------------------------

#define BK 4096          // edges per level-1 block
#define MAXBUK 256       // >= nbuk = ceil(2N/1024) = 196

typedef __attribute__((ext_vector_type(8))) short bf16x8;
typedef __attribute__((ext_vector_type(8))) unsigned short u16x8;
typedef __attribute__((ext_vector_type(4))) float f32x4;
typedef __attribute__((ext_vector_type(2))) float f32x2;

__device__ __forceinline__ ushort f2b(float x) {
    union { float f; unsigned u; } v; v.f = x;
    unsigned r = (v.u + 0x7FFF + ((v.u >> 16) & 1)) >> 16;   // RNE
    return (ushort)r;
}
__device__ __forceinline__ float b2f(ushort u) {
    union { unsigned u; float f; } v; v.u = (unsigned)u << 16;
    return v.f;
}
// decode 4 fp8 (one u32) and accumulate into a[0..3]
__device__ __forceinline__ void acc4(unsigned w, float* a) {
    f32x2 lo = __builtin_amdgcn_cvt_pk_f32_fp8((int)w, false);
    f32x2 hi = __builtin_amdgcn_cvt_pk_f32_fp8((int)w, true);
    a[0] += lo[0]; a[1] += lo[1]; a[2] += hi[0]; a[3] += hi[1];
}

// ---- fused front: [pack | bucket hist (LDS) | fp8 convert] by block range ----
__global__ __launch_bounds__(256) void k_front(
        const float* __restrict__ x_image, const float* __restrict__ x_text,
        const int* __restrict__ edge_i, const int* __restrict__ edge_t,
        const float* __restrict__ Wl_i, const float* __restrict__ Wl_t,
        const float* __restrict__ W_user, const float* __restrict__ b_user,
        const float* __restrict__ Wr_i, const float* __restrict__ Wr_t,
        const float* __restrict__ bl_i, const float* __restrict__ bl_t,
        unsigned char* __restrict__ xib, unsigned char* __restrict__ xtb,
        ushort* __restrict__ Bp, float* __restrict__ bias,
        int* __restrict__ counts,
        int N, int E, int nblkR, int nbuk, int nbP) {
    __shared__ int h[MAXBUK];
    const int bid = blockIdx.x;
    const int tid = threadIdx.x;
    const int NBLK = 2 * nblkR;

    if (bid < nbP) {
        // ---- pack Bp [512x128] = [Wl_i; Wl_t; W_user@(Wr_i+Wr_t)] + bias ----
        int i = bid * 256 + tid;                     // < 65536
        int j = i & 7, lane = (i >> 3) & 63, cf = (i >> 9) & 7, ks = i >> 12;
        int kk = ks * 32 + (lane >> 4) * 8 + j;
        int col = cf * 16 + (lane & 15);
        float v;
        if (kk < 128)      v = Wl_i[kk * 128 + col];
        else if (kk < 256) v = Wl_t[(kk - 128) * 128 + col];
        else {
            int k2 = kk - 256;
            float s = 0.f;
            for (int c1 = 0; c1 < 128; ++c1)
                s += W_user[k2 * 128 + c1] * (Wr_i[c1 * 128 + col] + Wr_t[c1 * 128 + col]);
            v = s;
        }
        Bp[i] = f2b(v);
        if (i < 128) {
            float b = bl_i[i] + bl_t[i];
            for (int k2 = 0; k2 < 128; ++k2)
                b += b_user[k2] * (Wr_i[k2 * 128 + i] + Wr_t[k2 * 128 + i]);
            bias[i] = b;
        }
    } else if (bid < nbP + NBLK) {
        // ---- level-1 histogram of bucket = key>>10, LDS atomics only ----
        int hb = bid - nbP;
        int rel = (hb >= nblkR) ? 1 : 0;
        int blk = hb - rel * nblkR;
        const int* eg = rel ? edge_t : edge_i;
        const int relN = rel * N;
        for (int i = tid; i < nbuk; i += 256) h[i] = 0;
        __syncthreads();
        int base = blk * BK;
        #pragma unroll
        for (int j = 0; j < 4; ++j) {
            int e = base + (j * 256 + tid) * 4;
            if (e + 3 < E) {
                int4 d4 = *reinterpret_cast<const int4*>(eg + E + e);
                atomicAdd(&h[(relN + d4.x) >> 10], 1);
                atomicAdd(&h[(relN + d4.y) >> 10], 1);
                atomicAdd(&h[(relN + d4.z) >> 10], 1);
                atomicAdd(&h[(relN + d4.w) >> 10], 1);
            } else {
                for (int q = 0; q < 4; ++q) {
                    int ee = e + q;
                    if (ee < E) atomicAdd(&h[(relN + eg[E + ee]) >> 10], 1);
                }
            }
        }
        __syncthreads();
        for (int i = tid; i < nbuk; i += 256) counts[(size_t)hb * nbuk + i] = h[i];
    } else {
        // ---- x_image/x_text f32 -> fp8 e4m3 (HW cvt, RNE) ----
        int t = (bid - nbP - NBLK) * 256 + tid;
        int n8 = N * 16;
        if (t >= 2 * n8) return;
        int relc = (t >= n8) ? 1 : 0;
        const float* src = relc ? x_text : x_image;
        unsigned char* dst = relc ? xtb : xib;
        int i = relc ? t - n8 : t;
        float4 f0 = *reinterpret_cast<const float4*>(src + (size_t)i * 8);
        float4 f1 = *reinterpret_cast<const float4*>(src + (size_t)i * 8 + 4);
        int w0 = 0, w1 = 0;
        w0 = __builtin_amdgcn_cvt_pk_fp8_f32(f0.x, f0.y, w0, false);
        w0 = __builtin_amdgcn_cvt_pk_fp8_f32(f0.z, f0.w, w0, true);
        w1 = __builtin_amdgcn_cvt_pk_fp8_f32(f1.x, f1.y, w1, false);
        w1 = __builtin_amdgcn_cvt_pk_fp8_f32(f1.z, f1.w, w1, true);
        *reinterpret_cast<uint2*>(dst + (size_t)i * 8) = make_uint2((unsigned)w0, (unsigned)w1);
    }
}

// ---- s1: per-bucket exclusive prefix over blocks (in-place) + totals ----
__global__ __launch_bounds__(256) void k_s1(int* __restrict__ counts,
                                            int* __restrict__ T,
                                            int NBLK, int nbuk) {
    __shared__ int a[512];
    __shared__ int ps[256];
    const int b = blockIdx.x, t = threadIdx.x;
    a[t]       = (t < NBLK)       ? counts[(size_t)t * nbuk + b] : 0;
    a[t + 256] = (t + 256 < NBLK) ? counts[(size_t)(t + 256) * nbuk + b] : 0;
    __syncthreads();
    int x0 = a[2 * t], x1 = a[2 * t + 1];
    int s = x0 + x1;
    ps[t] = s; __syncthreads();
    for (int off = 1; off < 256; off <<= 1) {
        int add = (t >= off) ? ps[t - off] : 0;
        __syncthreads();
        ps[t] += add;
        __syncthreads();
    }
    int ex = ps[t] - s;
    if (2 * t < NBLK)     counts[(size_t)(2 * t) * nbuk + b] = ex;
    if (2 * t + 1 < NBLK) counts[(size_t)(2 * t + 1) * nbuk + b] = ex + x0;
    if (t == 255) T[b] = ps[255];
}

// ---- s2: exclusive scan of bucket totals -> bucket bases ----
__global__ __launch_bounds__(256) void k_s2(const int* __restrict__ T,
                                            int* __restrict__ Bb,
                                            int* __restrict__ rowptr,
                                            int M, int Etot, int nbuk) {
    __shared__ int sh[256];
    int t = threadIdx.x;
    int v = (t < nbuk) ? T[t] : 0;
    sh[t] = v; __syncthreads();
    for (int off = 1; off < 256; off <<= 1) {
        int add = (t >= off) ? sh[t - off] : 0;
        __syncthreads();
        sh[t] += add;
        __syncthreads();
    }
    if (t < nbuk) Bb[t] = sh[t] - v;
    if (t == 0) { Bb[nbuk] = Etot; rowptr[M] = Etot; }
}

// ---- part1 (512 thr): scatter packed pairs into bucket regions ----
__global__ __launch_bounds__(512) void k_part1(
        const int* __restrict__ edge_i, const int* __restrict__ edge_t,
        const int* __restrict__ counts, const int* __restrict__ Bb,
        unsigned* __restrict__ pairs, int N, int E, int nblkR, int nbuk) {
    __shared__ int cur[MAXBUK];
    const int bid = blockIdx.x, tid = threadIdx.x;
    int rel = (bid >= nblkR) ? 1 : 0;
    int blk = bid - rel * nblkR;
    const int* eg = rel ? edge_t : edge_i;
    const int relN = rel * N;
    for (int i = tid; i < nbuk; i += 512)
        cur[i] = Bb[i] + counts[(size_t)bid * nbuk + i];
    __syncthreads();
    int base = blk * BK;
    #pragma unroll
    for (int j = 0; j < 2; ++j) {
        int e = base + (j * 512 + tid) * 4;
        if (e + 3 < E) {
            int4 d4 = *reinterpret_cast<const int4*>(eg + E + e);
            int4 s4 = *reinterpret_cast<const int4*>(eg + e);
            int k0 = relN + d4.x, k1 = relN + d4.y, k2 = relN + d4.z, k3 = relN + d4.w;
            int p0 = atomicAdd(&cur[k0 >> 10], 1);
            pairs[p0] = ((unsigned)(k0 & 1023) << 17) | (unsigned)s4.x;
            int p1 = atomicAdd(&cur[k1 >> 10], 1);
            pairs[p1] = ((unsigned)(k1 & 1023) << 17) | (unsigned)s4.y;
            int p2 = atomicAdd(&cur[k2 >> 10], 1);
            pairs[p2] = ((unsigned)(k2 & 1023) << 17) | (unsigned)s4.z;
            int p3 = atomicAdd(&cur[k3 >> 10], 1);
            pairs[p3] = ((unsigned)(k3 & 1023) << 17) | (unsigned)s4.w;
        } else {
            for (int q = 0; q < 4; ++q) {
                int ee = e + q;
                if (ee < E) {
                    int k0 = relN + eg[E + ee];
                    int p0 = atomicAdd(&cur[k0 >> 10], 1);
                    pairs[p0] = ((unsigned)(k0 & 1023) << 17) | (unsigned)eg[ee];
                }
            }
        }
    }
}

// ---- part2 (512 thr): per-bucket (1024 keys) hist/scan -> rowptr + col ----
__global__ __launch_bounds__(512) void k_part2(
        const unsigned* __restrict__ pairs, const int* __restrict__ Bb,
        int* __restrict__ rowptr, int* __restrict__ col, int M) {
    __shared__ int h[1024];
    __shared__ int ps[512];
    const int b = blockIdx.x, t = threadIdx.x;
    const int key0 = b << 10;
    const int beg = Bb[b], end = Bb[b + 1];
    h[t] = 0; h[t + 512] = 0;
    __syncthreads();
    for (int p = beg + t; p < end; p += 512)
        atomicAdd(&h[pairs[p] >> 17], 1);
    __syncthreads();
    int v0 = h[2 * t], v1 = h[2 * t + 1];
    int s = v0 + v1;
    ps[t] = s; __syncthreads();
    for (int off = 1; off < 512; off <<= 1) {
        int add = (t >= off) ? ps[t - off] : 0;
        __syncthreads();
        ps[t] += add;
        __syncthreads();
    }
    int run = ps[t] - s + beg;
    __syncthreads();
    int k = key0 + 2 * t;
    if (k < M) rowptr[k] = run;
    h[2 * t] = run; run += v0;
    if (k + 1 < M) rowptr[k + 1] = run;
    h[2 * t + 1] = run;
    __syncthreads();
    for (int p = beg + t; p < end; p += 512) {
        unsigned pr = pairs[p];
        int slot = atomicAdd(&h[pr >> 17], 1);
        col[slot] = (int)(pr & 0x1FFFFu);
    }
}

// ---- gather-mean: 8 lanes/node, 16B(16 fp8)/lane, unroll-4, bf16 means ----
__global__ __launch_bounds__(256) void k_gather_mean(
        const unsigned char* __restrict__ xib, const unsigned char* __restrict__ xtb,
        const int* __restrict__ rowptr, const int* __restrict__ col,
        ushort* __restrict__ mi, ushort* __restrict__ mt, int N) {
    int t = blockIdx.x * 256 + threadIdx.x;
    int node = t >> 3, lane = t & 7;
    if (node >= N) return;
    int rel = blockIdx.y;
    const unsigned char* xs = rel ? xtb : xib;
    ushort* mean = rel ? mt : mi;
    const int c0 = lane * 16;            // element (= byte) offset in 128-elem row
    int rb = rel * N + node;
    int beg = rowptr[rb], end = rowptr[rb + 1];
    float a[16];
    #pragma unroll
    for (int q = 0; q < 16; ++q) a[q] = 0.f;
    int j = beg;
    for (; j + 3 < end; j += 4) {
        int s0 = col[j], s1 = col[j + 1], s2 = col[j + 2], s3 = col[j + 3];
        uint4 v0 = *reinterpret_cast<const uint4*>(xs + (size_t)s0 * 128 + c0);
        uint4 v1 = *reinterpret_cast<const uint4*>(xs + (size_t)s1 * 128 + c0);
        uint4 v2 = *reinterpret_cast<const uint4*>(xs + (size_t)s2 * 128 + c0);
        uint4 v3 = *reinterpret_cast<const uint4*>(xs + (size_t)s3 * 128 + c0);
        acc4(v0.x, a + 0); acc4(v0.y, a + 4); acc4(v0.z, a + 8); acc4(v0.w, a + 12);
        acc4(v1.x, a + 0); acc4(v1.y, a + 4); acc4(v1.z, a + 8); acc4(v1.w, a + 12);
        acc4(v2.x, a + 0); acc4(v2.y, a + 4); acc4(v2.z, a + 8); acc4(v2.w, a + 12);
        acc4(v3.x, a + 0); acc4(v3.y, a + 4); acc4(v3.z, a + 8); acc4(v3.w, a + 12);
    }
    for (; j < end; ++j) {
        uint4 v0 = *reinterpret_cast<const uint4*>(xs + (size_t)col[j] * 128 + c0);
        acc4(v0.x, a + 0); acc4(v0.y, a + 4); acc4(v0.z, a + 8); acc4(v0.w, a + 12);
    }
    float r = (end > beg) ? 1.0f / (float)(end - beg) : 0.0f;
    u16x8 o0, o1;
    #pragma unroll
    for (int q = 0; q < 8; ++q) { o0[q] = f2b(a[q] * r); o1[q] = f2b(a[q + 8] * r); }
    *reinterpret_cast<u16x8*>(mean + (size_t)node * 128 + c0) = o0;
    *reinterpret_cast<u16x8*>(mean + (size_t)node * 128 + c0 + 8) = o1;
}

// ---- out = relu( [mi|mt|x_user](K=512) @ Bp + bias ) : MFMA, B in LDS ----
// 512 thr / 8 waves, 256 rows per block (32 rows/wave), B staged in 2x64KB.
__global__ __launch_bounds__(512) void k_final_mfma(
        const ushort* __restrict__ mi, const ushort* __restrict__ mt,
        const float* __restrict__ x_user, const ushort* __restrict__ Bp,
        const float* __restrict__ bias, float* __restrict__ out, int N) {
    __shared__ u16x8 bl8[4096];                  // 64 KB half of B
    const int tid = threadIdx.x;
    const int wid = tid >> 6, lane = tid & 63;
    const int r0g = blockIdx.x * 256 + wid * 32 + (lane & 15);
    const int rA0 = min(r0g, N - 1);
    const int rA1 = min(r0g + 16, N - 1);
    const int kh = (lane >> 4) * 8;
    f32x4 acc0[8] = {}, acc1[8] = {};

    const u16x8* Bp8 = reinterpret_cast<const u16x8*>(Bp);

    #pragma unroll
    for (int h = 0; h < 2; ++h) {
        // ---- stage 64KB half of B into LDS (linear copy) ----
        if (h) __syncthreads();                  // protect previous half's reads
        #pragma unroll
        for (int it = 0; it < 8; ++it)
            bl8[it * 512 + tid] = Bp8[h * 4096 + it * 512 + tid];
        __syncthreads();

        if (h == 0) {
            // ---- ks 0..7: A from mi/mt (bf16) ----
            #pragma unroll
            for (int ks = 0; ks < 8; ++ks) {
                const ushort* s = (ks < 4) ? mi : mt;
                bf16x8 a0 = *reinterpret_cast<const bf16x8*>(s + (size_t)rA0 * 128 + (ks & 3) * 32 + kh);
                bf16x8 a1 = *reinterpret_cast<const bf16x8*>(s + (size_t)rA1 * 128 + (ks & 3) * 32 + kh);
                #pragma unroll
                for (int cf = 0; cf < 8; ++cf) {
                    bf16x8 bb = *reinterpret_cast<const bf16x8*>(&bl8[(ks * 8 + cf) * 64 + lane]);
                    acc0[cf] = __builtin_amdgcn_mfma_f32_16x16x32_bf16(a0, bb, acc0[cf], 0, 0, 0);
                    acc1[cf] = __builtin_amdgcn_mfma_f32_16x16x32_bf16(a1, bb, acc1[cf], 0, 0, 0);
                }
            }
        } else {
            // ---- ks 8..15: A from x_user (f32, inline cvt) ----
            const float* Xr0 = x_user + (size_t)rA0 * 256;
            const float* Xr1 = x_user + (size_t)rA1 * 256;
            #pragma unroll
            for (int ks = 0; ks < 8; ++ks) {
                int k0 = ks * 32 + kh;
                float4 f0 = *reinterpret_cast<const float4*>(Xr0 + k0);
                float4 f1 = *reinterpret_cast<const float4*>(Xr0 + k0 + 4);
                float4 g0 = *reinterpret_cast<const float4*>(Xr1 + k0);
                float4 g1 = *reinterpret_cast<const float4*>(Xr1 + k0 + 4);
                bf16x8 a0, a1;
                a0[0] = (short)f2b(f0.x); a0[1] = (short)f2b(f0.y);
                a0[2] = (short)f2b(f0.z); a0[3] = (short)f2b(f0.w);
                a0[4] = (short)f2b(f1.x); a0[5] = (short)f2b(f1.y);
                a0[6] = (short)f2b(f1.z); a0[7] = (short)f2b(f1.w);
                a1[0] = (short)f2b(g0.x); a1[1] = (short)f2b(g0.y);
                a1[2] = (short)f2b(g0.z); a1[3] = (short)f2b(g0.w);
                a1[4] = (short)f2b(g1.x); a1[5] = (short)f2b(g1.y);
                a1[6] = (short)f2b(g1.z); a1[7] = (short)f2b(g1.w);
                #pragma unroll
                for (int cf = 0; cf < 8; ++cf) {
                    bf16x8 bb = *reinterpret_cast<const bf16x8*>(&bl8[(ks * 8 + cf) * 64 + lane]);
                    acc0[cf] = __builtin_amdgcn_mfma_f32_16x16x32_bf16(a0, bb, acc0[cf], 0, 0, 0);
                    acc1[cf] = __builtin_amdgcn_mfma_f32_16x16x32_bf16(a1, bb, acc1[cf], 0, 0, 0);
                }
            }
        }
    }

    // ---- epilogue: bias + relu + store (2 row groups) ----
    const int col0 = lane & 15;
    const int rbase = blockIdx.x * 256 + wid * 32 + (lane >> 4) * 4;
    #pragma unroll
    for (int cf = 0; cf < 8; ++cf) {
        int c = cf * 16 + col0;
        float bv = bias[c];
        #pragma unroll
        for (int r = 0; r < 4; ++r) {
            int row = rbase + r;
            if (row < N) out[(size_t)row * 128 + c] = fmaxf(acc0[cf][r] + bv, 0.f);
            int row2 = rbase + 16 + r;
            if (row2 < N) out[(size_t)row2 * 128 + c] = fmaxf(acc1[cf][r] + bv, 0.f);
        }
    }
}

extern "C" void kernel_launch(void* const* d_in, const int* in_sizes, int n_in,
                              void* d_out, int out_size, void* d_ws, size_t ws_size,
                              hipStream_t stream) {
    const float* x_user  = (const float*)d_in[0];
    const float* x_image = (const float*)d_in[1];
    const float* x_text  = (const float*)d_in[2];
    const int*   edge_i  = (const int*)d_in[3];
    const int*   edge_t  = (const int*)d_in[4];
    const float* W_user  = (const float*)d_in[5];
    const float* b_user  = (const float*)d_in[6];
    const float* Wl_img  = (const float*)d_in[7];
    const float* bl_img  = (const float*)d_in[8];
    const float* Wr_img  = (const float*)d_in[9];
    const float* Wl_txt  = (const float*)d_in[10];
    const float* bl_txt  = (const float*)d_in[11];
    const float* Wr_txt  = (const float*)d_in[12];

    const int N = in_sizes[0] / 256;   // 100000 nodes per type
    const int E = in_sizes[3] / 2;     // 800000 edges per relation
    const int M = 2 * N;
    const int nblkR = (E + BK - 1) / BK;           // 196
    const int NBLK = 2 * nblkR;                    // 392 (<=512 for k_s1)
    const int nbuk = (M + 1023) >> 10;             // 196 (<=MAXBUK)

    unsigned char* xib = (unsigned char*)d_ws;         // N*128 B (fp8)
    unsigned char* xtb = xib + (size_t)N * 128;        // N*128 B (fp8)
    ushort*   mi     = (ushort*)(xtb + (size_t)N * 128); // N*128 ushort
    ushort*   mt     = mi + (size_t)N * 128;           // N*128 ushort
    ushort*   Bp     = mt + (size_t)N * 128;           // 65536
    float*    bias   = (float*)(Bp + 65536);           // 128
    int*      counts = (int*)(bias + 128);             // NBLK*nbuk
    int*      T      = counts + (size_t)NBLK * nbuk;   // 256
    int*      Bb     = T + 256;                        // nbuk+1 (pad 260)
    int*      rowptr = Bb + 260;                       // M+4
    int*      col    = rowptr + (M + 4);               // 2E
    unsigned* pairs  = (unsigned*)(col + (size_t)2 * E); // 2E u32

    const int nbP = 256;                           // pack blocks (65536 thr)
    const int nbC = (2 * N * 16 + 255) / 256;      // convert blocks (img+txt)
    k_front<<<nbP + NBLK + nbC, 256, 0, stream>>>(
        x_image, x_text, edge_i, edge_t,
        Wl_img, Wl_txt, W_user, b_user, Wr_img, Wr_txt, bl_img, bl_txt,
        xib, xtb, Bp, bias, counts, N, E, nblkR, nbuk, nbP);

    k_s1<<<nbuk, 256, 0, stream>>>(counts, T, NBLK, nbuk);
    k_s2<<<1, 256, 0, stream>>>(T, Bb, rowptr, M, 2 * E, nbuk);
    k_part1<<<NBLK, 512, 0, stream>>>(edge_i, edge_t, counts, Bb, pairs,
                                      N, E, nblkR, nbuk);
    k_part2<<<nbuk, 512, 0, stream>>>(pairs, Bb, rowptr, col, M);

    {
        dim3 g((N * 8 + 255) / 256, 2);
        k_gather_mean<<<g, 256, 0, stream>>>(xib, xtb, rowptr, col, mi, mt, N);
    }

    k_final_mfma<<<(N + 255) / 256, 512, 0, stream>>>(
        mi, mt, x_user, Bp, bias, (float*)d_out, N);
}